// Round 2
// baseline (632.650 us; speedup 1.0000x reference)
//
#include <hip/hip_runtime.h>

typedef __bf16 bf16;
typedef __bf16 bf16x8 __attribute__((ext_vector_type(8)));
typedef __bf16 bf16x4 __attribute__((ext_vector_type(4)));
typedef float f32x4 __attribute__((ext_vector_type(4)));

#define DEVI __device__ __forceinline__

// problem constants
constexpr int Bc = 4, Sc = 1024, Hc = 2048, NHc = 16, HDc = 128;
constexpr int Tc = Bc * Sc;   // 4096
constexpr int Pc = NHc * HDc; // 2048

DEVI void async16(const void* g, void* l) {
  __builtin_amdgcn_global_load_lds(
      (const __attribute__((address_space(1))) unsigned int*)g,
      (__attribute__((address_space(3))) unsigned int*)l, 16, 0, 0);
}

// ---------------------------------------------------------------------------
// Generic GEMM: C[m][n] = sum_k A[m][k] * W[n][k]  (+ bias[n])
// A: M x K bf16 row-major, W: N x K bf16 row-major. M,N mult of 128, K mult of 32.
// m97-style: 128x128 tile, BK=32, 4 waves of 64x64, global_load_lds staging.
// ---------------------------------------------------------------------------
template <bool OUT_BF16>
__global__ __launch_bounds__(256, 2) void gemm_bt(
    const bf16* __restrict__ A, const bf16* __restrict__ W, void* __restrict__ Cout,
    const float* __restrict__ bias, int M, int N, int K) {
  __shared__ bf16 As[128 * 32];
  __shared__ bf16 Bs[128 * 32];
  const int nbx = N >> 7;
  const int bx = blockIdx.x % nbx, by = blockIdx.x / nbx;
  const int m0 = by * 128, n0 = bx * 128;
  const int tid = threadIdx.x;
  const int w = tid >> 6, l = tid & 63;
  const int wm = w >> 1, wn = w & 1;
  const int lr = l & 15;          // fragment row/col
  const int lk = (l >> 4) * 8;    // fragment k-offset

  f32x4 acc[4][4] = {};

  for (int k0 = 0; k0 < K; k0 += 32) {
#pragma unroll
    for (int c = 0; c < 2; ++c) {
      const int chunk = (w * 2 + c) * 64 + l;  // 16B chunk id, 0..511
      const int row = chunk >> 2, col = (chunk & 3) * 8;
      async16(A + (size_t)(m0 + row) * K + k0 + col, (char*)As + (w * 2 + c) * 1024);
      async16(W + (size_t)(n0 + row) * K + k0 + col, (char*)Bs + (w * 2 + c) * 1024);
    }
    __syncthreads();
    bf16x8 af[4], bfv[4];
#pragma unroll
    for (int m = 0; m < 4; ++m)
      af[m] = *(const bf16x8*)&As[(wm * 64 + m * 16 + lr) * 32 + lk];
#pragma unroll
    for (int n = 0; n < 4; ++n)
      bfv[n] = *(const bf16x8*)&Bs[(wn * 64 + n * 16 + lr) * 32 + lk];
#pragma unroll
    for (int m = 0; m < 4; ++m)
#pragma unroll
      for (int n = 0; n < 4; ++n)
        acc[m][n] = __builtin_amdgcn_mfma_f32_16x16x32_bf16(af[m], bfv[n], acc[m][n], 0, 0, 0);
    __syncthreads();
  }

#pragma unroll
  for (int n = 0; n < 4; ++n) {
    const int col = n0 + wn * 64 + n * 16 + lr;
    const float bv = bias ? bias[col] : 0.f;
#pragma unroll
    for (int m = 0; m < 4; ++m) {
#pragma unroll
      for (int j = 0; j < 4; ++j) {
        const int row = m0 + wm * 64 + m * 16 + ((l >> 4) << 2) + j;
        const float vv = acc[m][n][j] + bv;
        if (OUT_BF16)
          ((bf16*)Cout)[(size_t)row * N + col] = (bf16)vv;
        else
          ((float*)Cout)[(size_t)row * N + col] = vv;
      }
    }
  }
}

// ---------------------------------------------------------------------------
// fp32 -> bf16 weight conversion (vectorized by 4)
// ---------------------------------------------------------------------------
__global__ void k_f2b4(const float* __restrict__ in, bf16* __restrict__ out, int n4) {
  int i = blockIdx.x * 256 + threadIdx.x;
  if (i >= n4) return;
  float4 v = ((const float4*)in)[i];
  bf16x4 o = {(bf16)v.x, (bf16)v.y, (bf16)v.z, (bf16)v.w};
  ((bf16x4*)out)[i] = o;
}

// hidden fp32 -> hsb bf16, and conv1 interleaved input A1[t][2h+tap]
__global__ void k_build_a1(const float* __restrict__ hid, const float* __restrict__ lf1,
                           bf16* __restrict__ hsb, bf16* __restrict__ A1) {
  int idx = blockIdx.x * 256 + threadIdx.x;  // < T*H
  int t = idx >> 11, h = idx & 2047;
  float x = hid[idx];
  hsb[idx] = (bf16)x;
  float xp;
  if ((t & (Sc - 1)) == 0)
    xp = lf1[(t >> 10) * Hc + h];
  else
    xp = hid[idx - Hc];
  size_t a = ((size_t)t << 12) + 2 * h;
  A1[a] = (bf16)xp;
  A1[a + 1] = (bf16)x;
}

// conv2 interleaved input A2[t][2c+tap] from o1
__global__ void k_build_a2(const bf16* __restrict__ o1, const float* __restrict__ lf2,
                           bf16* __restrict__ A2) {
  int idx = blockIdx.x * 256 + threadIdx.x;  // < T*1024
  int t = idx >> 10, c = idx & 1023;
  bf16 cur = o1[idx];
  bf16 prev;
  if ((t & (Sc - 1)) == 0)
    prev = (bf16)lf2[(t >> 10) * 1024 + c];
  else
    prev = o1[idx - 1024];
  size_t a = ((size_t)t << 11) + 2 * c;
  A2[a] = prev;
  A2[a + 1] = cur;
}

// lf = rmsnorm(o2 + hid) * g   (one block per row, 256 thr x 8 elems)
__global__ __launch_bounds__(256) void k_rmsnorm(const bf16* __restrict__ o2,
                                                 const float* __restrict__ hid,
                                                 const float* __restrict__ g,
                                                 bf16* __restrict__ lf) {
  int t = blockIdx.x, tid = threadIdx.x;
  size_t base = ((size_t)t << 11) + tid * 8;
  bf16x8 ov = *(const bf16x8*)&o2[base];
  const float* hp = &hid[base];
  float vals[8];
  float ss = 0.f;
#pragma unroll
  for (int i = 0; i < 8; ++i) {
    float x = (float)ov[i] + hp[i];
    vals[i] = x;
    ss += x * x;
  }
#pragma unroll
  for (int off = 1; off < 64; off <<= 1) ss += __shfl_xor(ss, off);
  __shared__ float red[4];
  if ((tid & 63) == 0) red[tid >> 6] = ss;
  __syncthreads();
  float tot = red[0] + red[1] + red[2] + red[3];
  float inv = rsqrtf(tot * (1.f / 2048.f) + 1e-6f);
  bf16x8 o;
#pragma unroll
  for (int i = 0; i < 8; ++i) o[i] = (bf16)(vals[i] * inv * g[tid * 8 + i]);
  *(bf16x8*)&lf[base] = o;
}

// RoPE on qk (T,NH,256) -> qr,kr laid out (B,NH,S,HD) bf16
__global__ void k_rope(const bf16* __restrict__ qk, const float* __restrict__ rot,
                       bf16* __restrict__ qr, bf16* __restrict__ kr) {
  int bid = blockIdx.x;  // T*NH
  int n = bid & 15, t = bid >> 4;
  int s = t & (Sc - 1), b = t >> 10;
  int tid = threadIdx.x;
  int isk = tid >> 7, d = tid & 127;
  const bf16* src = qk + ((size_t)t << 12) + n * 256 + isk * 128;
  float val = (float)src[d];
  float outv = val;
  if (d < 64) {
    float f = rot[s * 64 + d];
    float c = cosf(f), sn = sinf(f);
    float other = (float)src[d ^ 32];
    outv = (d < 32) ? (val * c - other * sn) : (val * c + other * sn);
  }
  bf16* dst = isk ? kr : qr;
  dst[((size_t)((b * 16 + n) * 1024 + s) << 7) + d] = (bf16)outv;
}

// v (T,P) -> vT (B,NH,HD,S), 32x32 LDS tile transpose
__global__ void k_vt(const bf16* __restrict__ v, bf16* __restrict__ vT) {
  __shared__ bf16 tile[32][33];
  int bid = blockIdx.x;
  int dt = bid & 3;          // HD/32
  int st = (bid >> 2) & 31;  // S/32
  int bn = bid >> 7;         // b*NH+n
  int b = bn >> 4, n = bn & 15;
  int tx = threadIdx.x & 31, ty = threadIdx.x >> 5;  // 32 x 8
#pragma unroll
  for (int i = 0; i < 4; ++i) {
    int s = st * 32 + ty + i * 8;
    int d = dt * 32 + tx;
    tile[ty + i * 8][tx] = v[(size_t)(b * 1024 + s) * 2048 + n * 128 + d];
  }
  __syncthreads();
#pragma unroll
  for (int i = 0; i < 4; ++i) {
    int d = dt * 32 + ty + i * 8;
    int s = st * 32 + tx;
    vT[((size_t)(bn * 128 + d)) * 1024 + s] = tile[tx][ty + i * 8];
  }
}

// causal flash attention: 1 block per (b,h,q-tile64), 4 waves x 16 q-rows
__global__ __launch_bounds__(256) void k_attn(const bf16* __restrict__ qr,
                                              const bf16* __restrict__ kr,
                                              const bf16* __restrict__ vT,
                                              bf16* __restrict__ att) {
  __shared__ bf16 plds[4][16 * 64];
  int bid = blockIdx.x;
  int qt = bid & 15, bn = bid >> 4;
  int tid = threadIdx.x, w = tid >> 6, l = tid & 63;
  int lr = l & 15, hi = l >> 4;
  int qg0 = qt * 64 + w * 16;
  const bf16* qb = qr + ((size_t)(bn * 1024 + qg0) << 7);
  const bf16* kb = kr + ((size_t)bn << 17);
  const bf16* vb = vT + ((size_t)bn << 17);
  bf16x8 qf[4];
#pragma unroll
  for (int ks = 0; ks < 4; ++ks) qf[ks] = *(const bf16x8*)&qb[lr * 128 + ks * 32 + hi * 8];
  f32x4 oacc[8] = {};
  float mrow[4] = {-1e30f, -1e30f, -1e30f, -1e30f};
  float lrow[4] = {0.f, 0.f, 0.f, 0.f};
  const int nkb = (qg0 + 15 + 64) >> 6;
  const float scaling = 0.08838834764831845f;

  for (int kbt = 0; kbt < nkb; ++kbt) {
    f32x4 sacc[4] = {};
#pragma unroll
    for (int n = 0; n < 4; ++n)
#pragma unroll
      for (int ks = 0; ks < 4; ++ks) {
        bf16x8 kf = *(const bf16x8*)&kb[(size_t)(kbt * 64 + n * 16 + lr) * 128 + ks * 32 + hi * 8];
        sacc[n] = __builtin_amdgcn_mfma_f32_16x16x32_bf16(qf[ks], kf, sacc[n], 0, 0, 0);
      }
    const bool needmask = (kbt * 64 + 63 > qg0);
#pragma unroll
    for (int n = 0; n < 4; ++n) {
      int kg = kbt * 64 + n * 16 + lr;
#pragma unroll
      for (int j = 0; j < 4; ++j) {
        float sv = sacc[n][j] * scaling;
        if (needmask && kg > qg0 + hi * 4 + j) sv = -1e30f;
        sacc[n][j] = sv;
      }
    }
    float sf[4];
#pragma unroll
    for (int j = 0; j < 4; ++j) {
      float pm = fmaxf(fmaxf(sacc[0][j], sacc[1][j]), fmaxf(sacc[2][j], sacc[3][j]));
      pm = fmaxf(pm, __shfl_xor(pm, 1));
      pm = fmaxf(pm, __shfl_xor(pm, 2));
      pm = fmaxf(pm, __shfl_xor(pm, 4));
      pm = fmaxf(pm, __shfl_xor(pm, 8));
      float mn = fmaxf(mrow[j], pm);
      sf[j] = __expf(mrow[j] - mn);
      mrow[j] = mn;
    }
#pragma unroll
    for (int n = 0; n < 4; ++n)
#pragma unroll
      for (int j = 0; j < 4; ++j) sacc[n][j] = __expf(sacc[n][j] - mrow[j]);
#pragma unroll
    for (int j = 0; j < 4; ++j) {
      float ps = sacc[0][j] + sacc[1][j] + sacc[2][j] + sacc[3][j];
      ps += __shfl_xor(ps, 1);
      ps += __shfl_xor(ps, 2);
      ps += __shfl_xor(ps, 4);
      ps += __shfl_xor(ps, 8);
      lrow[j] = lrow[j] * sf[j] + ps;
    }
#pragma unroll
    for (int dt = 0; dt < 8; ++dt)
#pragma unroll
      for (int j = 0; j < 4; ++j) oacc[dt][j] *= sf[j];
#pragma unroll
    for (int n = 0; n < 4; ++n)
#pragma unroll
      for (int j = 0; j < 4; ++j)
        plds[w][(hi * 4 + j) * 64 + n * 16 + lr] = (bf16)sacc[n][j];
    // per-wave fence: waves have different trip counts, cannot __syncthreads here
    asm volatile("s_waitcnt lgkmcnt(0)" ::: "memory");
#pragma unroll
    for (int ks = 0; ks < 2; ++ks) {
      bf16x8 pf = *(const bf16x8*)&plds[w][lr * 64 + ks * 32 + hi * 8];
#pragma unroll
      for (int dt = 0; dt < 8; ++dt) {
        bf16x8 vf = *(const bf16x8*)&vb[(size_t)(dt * 16 + lr) * 1024 + kbt * 64 + ks * 32 + hi * 8];
        oacc[dt] = __builtin_amdgcn_mfma_f32_16x16x32_bf16(pf, vf, oacc[dt], 0, 0, 0);
      }
    }
  }
  int b = bn >> 4, hh = bn & 15;
#pragma unroll
  for (int j = 0; j < 4; ++j) {
    float inv = 1.f / lrow[j];
    int qg = qg0 + hi * 4 + j;
    size_t obase = ((size_t)(b * 1024 + qg) << 11) + hh * 128;
#pragma unroll
    for (int dt = 0; dt < 8; ++dt) att[obase + dt * 16 + lr] = (bf16)(oacc[dt][j] * inv);
  }
}

// ---------------------------------------------------------------------------
// Workspace plan (120 MB total, sequential liveness — one stream, in-order):
//   W    0-16    weight slot (reused: Wv, c1w, c2w, Wqk(16MB), Wo)
//   S0  16-48    A1 (32MB)            -> qkb (32MB)
//   S1  48-64    hsb                  -> lfb      -> vT
//   S2  64-80    v                    -> att
//   S3  80-88    o1
//   S4  88-104   A2                   -> qr
//   S5 104-120   o2                   -> kr
// ---------------------------------------------------------------------------
extern "C" void kernel_launch(void* const* d_in, const int* in_sizes, int n_in,
                              void* d_out, int out_size, void* d_ws, size_t ws_size,
                              hipStream_t stream) {
  const float* hid = (const float*)d_in[1];
  const float* rot = (const float*)d_in[2];
  const float* lf1 = (const float*)d_in[3];
  const float* lf2 = (const float*)d_in[4];
  const float* Wqk = (const float*)d_in[5];
  const float* Wv  = (const float*)d_in[6];
  const float* Wo  = (const float*)d_in[7];
  const float* c1w = (const float*)d_in[8];
  const float* c1b = (const float*)d_in[9];
  const float* c2w = (const float*)d_in[10];
  const float* c2b = (const float*)d_in[11];
  const float* lng = (const float*)d_in[12];
  float* outp = (float*)d_out;
  char* ws = (char*)d_ws;

  const size_t MB = 1ull << 20;
  bf16* Wslot = (bf16*)(ws + 0 * MB);    // 16MB shared weight slot
  bf16* A1    = (bf16*)(ws + 16 * MB);   // 32MB
  bf16* qkb   = A1;                      // alias (A1 dead after conv1 gemm)
  bf16* hsb   = (bf16*)(ws + 48 * MB);   // 16MB
  bf16* lfb   = hsb;                     // alias (hsb dead after Wv gemm)
  bf16* vT    = hsb;                     // alias (lfb dead after Wqk gemm)
  bf16* v     = (bf16*)(ws + 64 * MB);   // 16MB
  bf16* att   = v;                       // alias (v dead after k_vt)
  bf16* o1    = (bf16*)(ws + 80 * MB);   // 8MB
  bf16* A2    = (bf16*)(ws + 88 * MB);   // 16MB
  bf16* qr    = A2;                      // alias (A2 dead after conv2 gemm)
  bf16* o2    = (bf16*)(ws + 104 * MB);  // 16MB
  bf16* kr    = o2;                      // alias (o2 dead after rmsnorm)

  auto f2b = [&](const float* in, bf16* out, int n) {
    int n4 = n / 4;
    k_f2b4<<<(n4 + 255) / 256, 256, 0, stream>>>(in, out, n4);
  };

  // 1. v = hs @ Wv.T
  f2b(Wv, Wslot, 2048 * 2048);
  k_build_a1<<<Tc * Hc / 256, 256, 0, stream>>>(hid, lf1, hsb, A1);
  gemm_bt<true><<<(Pc / 128) * (Tc / 128), 256, 0, stream>>>(hsb, Wslot, v, nullptr, Tc, Pc, Hc);

  // 2. conv1 (as GEMM over interleaved taps)
  f2b(c1w, Wslot, 1024 * 2048 * 2);
  gemm_bt<true><<<(1024 / 128) * (Tc / 128), 256, 0, stream>>>(A1, Wslot, o1, c1b, Tc, 1024, 4096);

  // 3. conv2
  k_build_a2<<<Tc * 1024 / 256, 256, 0, stream>>>(o1, lf2, A2);
  f2b(c2w, Wslot, 2048 * 1024 * 2);
  gemm_bt<true><<<(2048 / 128) * (Tc / 128), 256, 0, stream>>>(A2, Wslot, o2, c2b, Tc, 2048, 2048);

  // 4. residual + rmsnorm
  k_rmsnorm<<<Tc, 256, 0, stream>>>(o2, hid, lng, lfb);

  // 5. qk projection
  f2b(Wqk, Wslot, 4096 * 2048);
  gemm_bt<true><<<(4096 / 128) * (Tc / 128), 256, 0, stream>>>(lfb, Wslot, qkb, nullptr, Tc, 4096, 2048);

  // 6. rope, V transpose, attention
  k_rope<<<Tc * NHc, 256, 0, stream>>>(qkb, rot, qr, kr);
  k_vt<<<64 * 32 * 4, 256, 0, stream>>>(v, vT);
  k_attn<<<Bc * NHc * (Sc / 64), 256, 0, stream>>>(qr, kr, vT, att);

  // 7. output projection (fp32 out)
  f2b(Wo, Wslot, 2048 * 2048);
  gemm_bt<false><<<(2048 / 128) * (Tc / 128), 256, 0, stream>>>(att, Wslot, outp, nullptr, Tc, 2048, 2048);
}

// Round 3
// 455.250 us; speedup vs baseline: 1.3897x; 1.3897x over previous
//
#include <hip/hip_runtime.h>

typedef __bf16 bf16;
typedef __bf16 bf16x8 __attribute__((ext_vector_type(8)));
typedef __bf16 bf16x4 __attribute__((ext_vector_type(4)));
typedef float f32x4 __attribute__((ext_vector_type(4)));

#define DEVI __device__ __forceinline__

// problem constants
constexpr int Bc = 4, Sc = 1024, Hc = 2048, NHc = 16, HDc = 128;
constexpr int Tc = Bc * Sc;   // 4096
constexpr int Pc = NHc * HDc; // 2048

DEVI void async16(const void* g, void* l) {
  __builtin_amdgcn_global_load_lds(
      (const __attribute__((address_space(1))) unsigned int*)g,
      (__attribute__((address_space(3))) unsigned int*)l, 16, 0, 0);
}

// ---------------------------------------------------------------------------
// Generic GEMM: C[m][n] = sum_k A[m][k] * W[n][k]  (+ bias[n])
// A: M x K bf16 row-major, W: N x K bf16 row-major. M,N mult of 128, K mult of 32.
// m97-style: 128x128 tile, BK=32, 4 waves of 64x64, global_load_lds staging.
// ---------------------------------------------------------------------------
template <bool OUT_BF16>
__global__ __launch_bounds__(256, 2) void gemm_bt(
    const bf16* __restrict__ A, const bf16* __restrict__ W, void* __restrict__ Cout,
    const float* __restrict__ bias, int M, int N, int K) {
  __shared__ bf16 As[128 * 32];
  __shared__ bf16 Bs[128 * 32];
  const int nbx = N >> 7;
  const int bx = blockIdx.x % nbx, by = blockIdx.x / nbx;
  const int m0 = by * 128, n0 = bx * 128;
  const int tid = threadIdx.x;
  const int w = tid >> 6, l = tid & 63;
  const int wm = w >> 1, wn = w & 1;
  const int lr = l & 15;          // fragment row/col
  const int lk = (l >> 4) * 8;    // fragment k-offset

  f32x4 acc[4][4] = {};

  for (int k0 = 0; k0 < K; k0 += 32) {
#pragma unroll
    for (int c = 0; c < 2; ++c) {
      const int chunk = (w * 2 + c) * 64 + l;  // 16B chunk id, 0..511
      const int row = chunk >> 2, col = (chunk & 3) * 8;
      async16(A + (size_t)(m0 + row) * K + k0 + col, (char*)As + (w * 2 + c) * 1024);
      async16(W + (size_t)(n0 + row) * K + k0 + col, (char*)Bs + (w * 2 + c) * 1024);
    }
    __syncthreads();
    bf16x8 af[4], bfv[4];
#pragma unroll
    for (int m = 0; m < 4; ++m)
      af[m] = *(const bf16x8*)&As[(wm * 64 + m * 16 + lr) * 32 + lk];
#pragma unroll
    for (int n = 0; n < 4; ++n)
      bfv[n] = *(const bf16x8*)&Bs[(wn * 64 + n * 16 + lr) * 32 + lk];
#pragma unroll
    for (int m = 0; m < 4; ++m)
#pragma unroll
      for (int n = 0; n < 4; ++n)
        acc[m][n] = __builtin_amdgcn_mfma_f32_16x16x32_bf16(af[m], bfv[n], acc[m][n], 0, 0, 0);
    __syncthreads();
  }

#pragma unroll
  for (int n = 0; n < 4; ++n) {
    const int col = n0 + wn * 64 + n * 16 + lr;
    const float bv = bias ? bias[col] : 0.f;
#pragma unroll
    for (int m = 0; m < 4; ++m) {
#pragma unroll
      for (int j = 0; j < 4; ++j) {
        const int row = m0 + wm * 64 + m * 16 + ((l >> 4) << 2) + j;
        const float vv = acc[m][n][j] + bv;
        if (OUT_BF16)
          ((bf16*)Cout)[(size_t)row * N + col] = (bf16)vv;
        else
          ((float*)Cout)[(size_t)row * N + col] = vv;
      }
    }
  }
}

// ---------------------------------------------------------------------------
// fp32 -> bf16 weight conversion (vectorized by 4)
// ---------------------------------------------------------------------------
__global__ void k_f2b4(const float* __restrict__ in, bf16* __restrict__ out, int n4) {
  int i = blockIdx.x * 256 + threadIdx.x;
  if (i >= n4) return;
  float4 v = ((const float4*)in)[i];
  bf16x4 o = {(bf16)v.x, (bf16)v.y, (bf16)v.z, (bf16)v.w};
  ((bf16x4*)out)[i] = o;
}

// hidden fp32 -> hsb bf16, and conv1 interleaved input A1[t][2h+tap]
__global__ void k_build_a1(const float* __restrict__ hid, const float* __restrict__ lf1,
                           bf16* __restrict__ hsb, bf16* __restrict__ A1) {
  int idx = blockIdx.x * 256 + threadIdx.x;  // < T*H
  int t = idx >> 11, h = idx & 2047;
  float x = hid[idx];
  hsb[idx] = (bf16)x;
  float xp;
  if ((t & (Sc - 1)) == 0)
    xp = lf1[(t >> 10) * Hc + h];
  else
    xp = hid[idx - Hc];
  size_t a = ((size_t)t << 12) + 2 * h;
  A1[a] = (bf16)xp;
  A1[a + 1] = (bf16)x;
}

// conv2 interleaved input A2[t][2c+tap] from o1
__global__ void k_build_a2(const bf16* __restrict__ o1, const float* __restrict__ lf2,
                           bf16* __restrict__ A2) {
  int idx = blockIdx.x * 256 + threadIdx.x;  // < T*1024
  int t = idx >> 10, c = idx & 1023;
  bf16 cur = o1[idx];
  bf16 prev;
  if ((t & (Sc - 1)) == 0)
    prev = (bf16)lf2[(t >> 10) * 1024 + c];
  else
    prev = o1[idx - 1024];
  size_t a = ((size_t)t << 11) + 2 * c;
  A2[a] = prev;
  A2[a + 1] = cur;
}

// lf = rmsnorm(o2 + hid) * g   (one block per row, 256 thr x 8 elems)
__global__ __launch_bounds__(256) void k_rmsnorm(const bf16* __restrict__ o2,
                                                 const float* __restrict__ hid,
                                                 const float* __restrict__ g,
                                                 bf16* __restrict__ lf) {
  int t = blockIdx.x, tid = threadIdx.x;
  size_t base = ((size_t)t << 11) + tid * 8;
  bf16x8 ov = *(const bf16x8*)&o2[base];
  const float* hp = &hid[base];
  float vals[8];
  float ss = 0.f;
#pragma unroll
  for (int i = 0; i < 8; ++i) {
    float x = (float)ov[i] + hp[i];
    vals[i] = x;
    ss += x * x;
  }
#pragma unroll
  for (int off = 1; off < 64; off <<= 1) ss += __shfl_xor(ss, off);
  __shared__ float red[4];
  if ((tid & 63) == 0) red[tid >> 6] = ss;
  __syncthreads();
  float tot = red[0] + red[1] + red[2] + red[3];
  float inv = rsqrtf(tot * (1.f / 2048.f) + 1e-6f);
  bf16x8 o;
#pragma unroll
  for (int i = 0; i < 8; ++i) o[i] = (bf16)(vals[i] * inv * g[tid * 8 + i]);
  *(bf16x8*)&lf[base] = o;
}

// RoPE on qk (T,NH,256) -> qr,kr laid out (B,NH,S,HD) bf16
__global__ void k_rope(const bf16* __restrict__ qk, const float* __restrict__ rot,
                       bf16* __restrict__ qr, bf16* __restrict__ kr) {
  int bid = blockIdx.x;  // T*NH
  int n = bid & 15, t = bid >> 4;
  int s = t & (Sc - 1), b = t >> 10;
  int tid = threadIdx.x;
  int isk = tid >> 7, d = tid & 127;
  const bf16* src = qk + ((size_t)t << 12) + n * 256 + isk * 128;
  float val = (float)src[d];
  float outv = val;
  if (d < 64) {
    float f = rot[s * 64 + d];
    float c = cosf(f), sn = sinf(f);
    float other = (float)src[d ^ 32];
    outv = (d < 32) ? (val * c - other * sn) : (val * c + other * sn);
  }
  bf16* dst = isk ? kr : qr;
  dst[((size_t)((b * 16 + n) * 1024 + s) << 7) + d] = (bf16)outv;
}

// v (T,P) -> vT (B,NH,HD,S), 32x32 LDS tile transpose
__global__ void k_vt(const bf16* __restrict__ v, bf16* __restrict__ vT) {
  __shared__ bf16 tile[32][33];
  int bid = blockIdx.x;
  int dt = bid & 3;          // HD/32
  int st = (bid >> 2) & 31;  // S/32
  int bn = bid >> 7;         // b*NH+n
  int b = bn >> 4, n = bn & 15;
  int tx = threadIdx.x & 31, ty = threadIdx.x >> 5;  // 32 x 8
#pragma unroll
  for (int i = 0; i < 4; ++i) {
    int s = st * 32 + ty + i * 8;
    int d = dt * 32 + tx;
    tile[ty + i * 8][tx] = v[(size_t)(b * 1024 + s) * 2048 + n * 128 + d];
  }
  __syncthreads();
#pragma unroll
  for (int i = 0; i < 4; ++i) {
    int d = dt * 32 + ty + i * 8;
    int s = st * 32 + tx;
    vT[((size_t)(bn * 128 + d)) * 1024 + s] = tile[tx][ty + i * 8];
  }
}

// ---------------------------------------------------------------------------
// causal flash attention v2: LDS-staged K/V, double-buffered global_load_lds,
// balanced q-tile pairs (pr, 15-pr), XCD-local (b,h) mapping.
// Block: 256 thr (4 waves x 16 q-rows), KV tile = 64. LDS 72KB -> 2 blk/CU.
// ---------------------------------------------------------------------------
__global__ __launch_bounds__(256, 2) void k_attn(const bf16* __restrict__ qr,
                                                 const bf16* __restrict__ kr,
                                                 const bf16* __restrict__ vT,
                                                 bf16* __restrict__ att) {
  __shared__ bf16 Ks[2][64 * 128];   // [tilebuf][krow][d]  (XOR-swizzled 16B groups)
  __shared__ bf16 Vs[2][128 * 64];   // [tilebuf][d][kcol]  (XOR-swizzled 16B groups)
  __shared__ bf16 plds[4][16 * 64];
  const int bid = blockIdx.x;
  // XCD-local mapping: all 8 pair-blocks of one (b,h) land on one XCD
  const int xcd = bid & 7, jj = bid >> 3;
  const int bn = xcd * 8 + (jj >> 3);
  const int pr = jj & 7;
  const int tid = threadIdx.x, w = tid >> 6, l = tid & 63;
  const int lr = l & 15, hi = l >> 4;
  const bf16* kb = kr + ((size_t)bn << 17);
  const bf16* vb = vT + ((size_t)bn << 17);
  const int b = bn >> 4, hh = bn & 15;
  const float scaling = 0.08838834764831845f;

  auto stage = [&](int buf, int kt) {
    // K tile: 64 rows x 256B; source col-group pre-swizzled (rule 21)
#pragma unroll
    for (int c = 0; c < 4; ++c) {
      int chunk = c * 256 + tid;
      int prow = chunk >> 4, pcg = chunk & 15;
      async16(kb + ((size_t)(kt * 64 + prow) << 7) + ((pcg ^ (prow & 7)) << 3),
              (char*)&Ks[buf][0] + chunk * 16);
    }
    // V tile: 128 rows x 128B
#pragma unroll
    for (int c = 0; c < 4; ++c) {
      int chunk = c * 256 + tid;
      int prow = chunk >> 3, pcg = chunk & 7;
      async16(vb + ((size_t)prow << 10) + kt * 64 + ((pcg ^ (prow & 7)) << 3),
              (char*)&Vs[buf][0] + chunk * 16);
    }
  };

#pragma unroll 1
  for (int phase = 0; phase < 2; ++phase) {
    const int qt = phase ? (15 - pr) : pr;
    const int qg0 = qt * 64 + w * 16;
    const bf16* qb = qr + ((size_t)(bn * 1024 + qg0) << 7);
    bf16x8 qf[4];
#pragma unroll
    for (int ks = 0; ks < 4; ++ks) qf[ks] = *(const bf16x8*)&qb[lr * 128 + ks * 32 + hi * 8];
    f32x4 oacc[8] = {};
    float mrow[4] = {-1e30f, -1e30f, -1e30f, -1e30f};
    float lrow[4] = {0.f, 0.f, 0.f, 0.f};
    const int nkb = qt + 1;  // block-uniform trip count

    stage(0, 0);
    __syncthreads();  // compiler drains vmcnt(0) before s_barrier

    for (int kbt = 0; kbt < nkb; ++kbt) {
      const int cur = kbt & 1;
      if (kbt + 1 < nkb) stage(cur ^ 1, kbt + 1);  // prefetch next tile (async)

      // ---- QK^T from LDS (swizzled reads) ----
      f32x4 sacc[4] = {};
#pragma unroll
      for (int n = 0; n < 4; ++n) {
        const int krow = n * 16 + lr;
#pragma unroll
        for (int ks = 0; ks < 4; ++ks) {
          bf16x8 kf = *(const bf16x8*)&Ks[cur][(krow << 7) + ((((ks << 2) | hi) ^ (krow & 7)) << 3)];
          sacc[n] = __builtin_amdgcn_mfma_f32_16x16x32_bf16(qf[ks], kf, sacc[n], 0, 0, 0);
        }
      }
      // ---- mask + online softmax ----
      const bool needmask = (kbt * 64 + 63 > qg0);
#pragma unroll
      for (int n = 0; n < 4; ++n) {
        int kg = kbt * 64 + n * 16 + lr;
#pragma unroll
        for (int j = 0; j < 4; ++j) {
          float sv = sacc[n][j] * scaling;
          if (needmask && kg > qg0 + hi * 4 + j) sv = -1e30f;
          sacc[n][j] = sv;
        }
      }
      float sf[4];
#pragma unroll
      for (int j = 0; j < 4; ++j) {
        float pm = fmaxf(fmaxf(sacc[0][j], sacc[1][j]), fmaxf(sacc[2][j], sacc[3][j]));
        pm = fmaxf(pm, __shfl_xor(pm, 1));
        pm = fmaxf(pm, __shfl_xor(pm, 2));
        pm = fmaxf(pm, __shfl_xor(pm, 4));
        pm = fmaxf(pm, __shfl_xor(pm, 8));
        float mn = fmaxf(mrow[j], pm);
        sf[j] = __expf(mrow[j] - mn);
        mrow[j] = mn;
      }
#pragma unroll
      for (int n = 0; n < 4; ++n)
#pragma unroll
        for (int j = 0; j < 4; ++j) sacc[n][j] = __expf(sacc[n][j] - mrow[j]);
#pragma unroll
      for (int j = 0; j < 4; ++j) {
        float ps = sacc[0][j] + sacc[1][j] + sacc[2][j] + sacc[3][j];
        ps += __shfl_xor(ps, 1);
        ps += __shfl_xor(ps, 2);
        ps += __shfl_xor(ps, 4);
        ps += __shfl_xor(ps, 8);
        lrow[j] = lrow[j] * sf[j] + ps;
      }
#pragma unroll
      for (int dt = 0; dt < 8; ++dt)
#pragma unroll
        for (int j = 0; j < 4; ++j) oacc[dt][j] *= sf[j];
      // ---- P -> LDS (per-wave), PV from LDS ----
#pragma unroll
      for (int n = 0; n < 4; ++n)
#pragma unroll
        for (int j = 0; j < 4; ++j)
          plds[w][(hi * 4 + j) * 64 + n * 16 + lr] = (bf16)sacc[n][j];
      asm volatile("s_waitcnt lgkmcnt(0)" ::: "memory");
#pragma unroll
      for (int ks2 = 0; ks2 < 2; ++ks2) {
        bf16x8 pf = *(const bf16x8*)&plds[w][lr * 64 + ks2 * 32 + hi * 8];
#pragma unroll
        for (int dt = 0; dt < 8; ++dt) {
          const int vrow = dt * 16 + lr;
          bf16x8 vf = *(const bf16x8*)&Vs[cur][(vrow << 6) + ((((ks2 << 2) | hi) ^ (lr & 7)) << 3)];
          oacc[dt] = __builtin_amdgcn_mfma_f32_16x16x32_bf16(pf, vf, oacc[dt], 0, 0, 0);
        }
      }
      __syncthreads();  // stage(kbt+1) drained + all reads of buf cur^1 done
    }

    // ---- writeout ----
#pragma unroll
    for (int j = 0; j < 4; ++j) {
      float inv = 1.f / lrow[j];
      int qg = qg0 + hi * 4 + j;
      size_t obase = ((size_t)(b * 1024 + qg) << 11) + hh * 128;
#pragma unroll
      for (int dt = 0; dt < 8; ++dt) att[obase + dt * 16 + lr] = (bf16)(oacc[dt][j] * inv);
    }
  }
}

// ---------------------------------------------------------------------------
// Workspace plan (120 MB total, sequential liveness — one stream, in-order):
//   W    0-16    weight slot (reused: Wv, c1w, c2w, Wqk(16MB), Wo)
//   S0  16-48    A1 (32MB)            -> qkb (32MB)
//   S1  48-64    hsb                  -> lfb      -> vT
//   S2  64-80    v                    -> att
//   S3  80-88    o1
//   S4  88-104   A2                   -> qr
//   S5 104-120   o2                   -> kr
// ---------------------------------------------------------------------------
extern "C" void kernel_launch(void* const* d_in, const int* in_sizes, int n_in,
                              void* d_out, int out_size, void* d_ws, size_t ws_size,
                              hipStream_t stream) {
  const float* hid = (const float*)d_in[1];
  const float* rot = (const float*)d_in[2];
  const float* lf1 = (const float*)d_in[3];
  const float* lf2 = (const float*)d_in[4];
  const float* Wqk = (const float*)d_in[5];
  const float* Wv  = (const float*)d_in[6];
  const float* Wo  = (const float*)d_in[7];
  const float* c1w = (const float*)d_in[8];
  const float* c1b = (const float*)d_in[9];
  const float* c2w = (const float*)d_in[10];
  const float* c2b = (const float*)d_in[11];
  const float* lng = (const float*)d_in[12];
  float* outp = (float*)d_out;
  char* ws = (char*)d_ws;

  const size_t MB = 1ull << 20;
  bf16* Wslot = (bf16*)(ws + 0 * MB);    // 16MB shared weight slot
  bf16* A1    = (bf16*)(ws + 16 * MB);   // 32MB
  bf16* qkb   = A1;                      // alias (A1 dead after conv1 gemm)
  bf16* hsb   = (bf16*)(ws + 48 * MB);   // 16MB
  bf16* lfb   = hsb;                     // alias (hsb dead after Wv gemm)
  bf16* vT    = hsb;                     // alias (lfb dead after Wqk gemm)
  bf16* v     = (bf16*)(ws + 64 * MB);   // 16MB
  bf16* att   = v;                       // alias (v dead after k_vt)
  bf16* o1    = (bf16*)(ws + 80 * MB);   // 8MB
  bf16* A2    = (bf16*)(ws + 88 * MB);   // 16MB
  bf16* qr    = A2;                      // alias (A2 dead after conv2 gemm)
  bf16* o2    = (bf16*)(ws + 104 * MB);  // 16MB
  bf16* kr    = o2;                      // alias (o2 dead after rmsnorm)

  auto f2b = [&](const float* in, bf16* out, int n) {
    int n4 = n / 4;
    k_f2b4<<<(n4 + 255) / 256, 256, 0, stream>>>(in, out, n4);
  };

  // 1. v = hs @ Wv.T
  f2b(Wv, Wslot, 2048 * 2048);
  k_build_a1<<<Tc * Hc / 256, 256, 0, stream>>>(hid, lf1, hsb, A1);
  gemm_bt<true><<<(Pc / 128) * (Tc / 128), 256, 0, stream>>>(hsb, Wslot, v, nullptr, Tc, Pc, Hc);

  // 2. conv1 (as GEMM over interleaved taps)
  f2b(c1w, Wslot, 1024 * 2048 * 2);
  gemm_bt<true><<<(1024 / 128) * (Tc / 128), 256, 0, stream>>>(A1, Wslot, o1, c1b, Tc, 1024, 4096);

  // 3. conv2
  k_build_a2<<<Tc * 1024 / 256, 256, 0, stream>>>(o1, lf2, A2);
  f2b(c2w, Wslot, 2048 * 1024 * 2);
  gemm_bt<true><<<(2048 / 128) * (Tc / 128), 256, 0, stream>>>(A2, Wslot, o2, c2b, Tc, 2048, 2048);

  // 4. residual + rmsnorm
  k_rmsnorm<<<Tc, 256, 0, stream>>>(o2, hid, lng, lfb);

  // 5. qk projection
  f2b(Wqk, Wslot, 4096 * 2048);
  gemm_bt<true><<<(4096 / 128) * (Tc / 128), 256, 0, stream>>>(lfb, Wslot, qkb, nullptr, Tc, 4096, 2048);

  // 6. rope, V transpose, attention (balanced pairs: 8 blocks per (b,h))
  k_rope<<<Tc * NHc, 256, 0, stream>>>(qkb, rot, qr, kr);
  k_vt<<<64 * 32 * 4, 256, 0, stream>>>(v, vT);
  k_attn<<<Bc * NHc * 8, 256, 0, stream>>>(qr, kr, vT, att);

  // 7. output projection (fp32 out)
  f2b(Wo, Wslot, 2048 * 2048);
  gemm_bt<false><<<(2048 / 128) * (Tc / 128), 256, 0, stream>>>(att, Wslot, outp, nullptr, Tc, 2048, 2048);
}

// Round 4
// 416.531 us; speedup vs baseline: 1.5189x; 1.0930x over previous
//
#include <hip/hip_runtime.h>

typedef __bf16 bf16;
typedef __bf16 bf16x8 __attribute__((ext_vector_type(8)));
typedef __bf16 bf16x4 __attribute__((ext_vector_type(4)));
typedef float f32x4 __attribute__((ext_vector_type(4)));

#define DEVI __device__ __forceinline__

// problem constants
constexpr int Bc = 4, Sc = 1024, Hc = 2048, NHc = 16, HDc = 128;
constexpr int Tc = Bc * Sc;   // 4096
constexpr int Pc = NHc * HDc; // 2048

DEVI void async16(const void* g, void* l) {
  __builtin_amdgcn_global_load_lds(
      (const __attribute__((address_space(1))) unsigned int*)g,
      (__attribute__((address_space(3))) unsigned int*)l, 16, 0, 0);
}

// ---------------------------------------------------------------------------
// Generic GEMM: C[m][n] = sum_k A[m][k] * W[n][k]  (+ bias[n])
// A: M x K bf16 row-major, W: N x K bf16 row-major. M,N mult of 128, K mult of 64.
// v2: BK=64, double-buffered LDS w/ prefetch-issue-early (T3 2-phase),
// XOR-swizzled LDS (group ^= row&7, both-sides per rule 21), XCD-chunked bids.
// LDS 64KB -> 2 blocks/CU.
// ---------------------------------------------------------------------------
template <bool OUT_BF16>
__global__ __launch_bounds__(256, 2) void gemm_bt(
    const bf16* __restrict__ A, const bf16* __restrict__ W, void* __restrict__ Cout,
    const float* __restrict__ bias, int M, int N, int K) {
  __shared__ bf16 As[2][128 * 64];
  __shared__ bf16 Bs[2][128 * 64];
  const int nbx = N >> 7;
  const int nwg = (M >> 7) * nbx;
  // bijective XCD chunking (nwg % 8 == 0 for all our shapes)
  const int wgid = (blockIdx.x & 7) * (nwg >> 3) + (blockIdx.x >> 3);
  const int bx = wgid % nbx, by = wgid / nbx;
  const int m0 = by * 128, n0 = bx * 128;
  const int tid = threadIdx.x;
  const int w = tid >> 6, l = tid & 63;
  const int wm = w >> 1, wn = w & 1;
  const int lr = l & 15;        // fragment row/col
  const int hi = l >> 4;        // fragment k-group (8 elems each)

  auto stage = [&](int buf, int k0) {
    // 128 rows x 64 cols bf16 = 1024 x 16B chunks per matrix.
    // LDS dest linear; global source col-group inverse-swizzled (rule 21).
#pragma unroll
    for (int c = 0; c < 4; ++c) {
      const int chunk = c * 256 + tid;
      const int prow = chunk >> 3, pcg = chunk & 7;
      const int gcol = ((pcg ^ (prow & 7)) << 3);
      async16(A + (size_t)(m0 + prow) * K + k0 + gcol, (char*)&As[buf][0] + chunk * 16);
      async16(W + (size_t)(n0 + prow) * K + k0 + gcol, (char*)&Bs[buf][0] + chunk * 16);
    }
  };

  f32x4 acc[4][4] = {};
  const int nk = K >> 6;

  stage(0, 0);
  __syncthreads();

  for (int t = 0; t < nk; ++t) {
    const int cur = t & 1;
    if (t + 1 < nk) stage(cur ^ 1, (t + 1) << 6);  // async prefetch under compute

    bf16x8 af[4][2], bfv[4][2];
#pragma unroll
    for (int m = 0; m < 4; ++m) {
      const int r = wm * 64 + m * 16 + lr;
#pragma unroll
      for (int ks = 0; ks < 2; ++ks)
        af[m][ks] = *(const bf16x8*)((const char*)&As[cur][0] + r * 128 +
                                     ((((ks << 2) | hi) ^ (r & 7)) << 4));
    }
#pragma unroll
    for (int n = 0; n < 4; ++n) {
      const int r = wn * 64 + n * 16 + lr;
#pragma unroll
      for (int ks = 0; ks < 2; ++ks)
        bfv[n][ks] = *(const bf16x8*)((const char*)&Bs[cur][0] + r * 128 +
                                      ((((ks << 2) | hi) ^ (r & 7)) << 4));
    }
#pragma unroll
    for (int ks = 0; ks < 2; ++ks)
#pragma unroll
      for (int m = 0; m < 4; ++m)
#pragma unroll
        for (int n = 0; n < 4; ++n)
          acc[m][n] = __builtin_amdgcn_mfma_f32_16x16x32_bf16(af[m][ks], bfv[n][ks], acc[m][n], 0, 0, 0);

    __syncthreads();  // orders this iter's reads before next iter's DMA writes
  }

#pragma unroll
  for (int n = 0; n < 4; ++n) {
    const int col = n0 + wn * 64 + n * 16 + lr;
    const float bv = bias ? bias[col] : 0.f;
#pragma unroll
    for (int m = 0; m < 4; ++m) {
#pragma unroll
      for (int j = 0; j < 4; ++j) {
        const int row = m0 + wm * 64 + m * 16 + (hi << 2) + j;
        const float vv = acc[m][n][j] + bv;
        if (OUT_BF16)
          ((bf16*)Cout)[(size_t)row * N + col] = (bf16)vv;
        else
          ((float*)Cout)[(size_t)row * N + col] = vv;
      }
    }
  }
}

// ---------------------------------------------------------------------------
// fp32 -> bf16 weight conversion (vectorized by 4)
// ---------------------------------------------------------------------------
__global__ void k_f2b4(const float* __restrict__ in, bf16* __restrict__ out, int n4) {
  int i = blockIdx.x * 256 + threadIdx.x;
  if (i >= n4) return;
  float4 v = ((const float4*)in)[i];
  bf16x4 o = {(bf16)v.x, (bf16)v.y, (bf16)v.z, (bf16)v.w};
  ((bf16x4*)out)[i] = o;
}

// hidden fp32 -> hsb bf16, and conv1 interleaved input A1[t][2h+tap]
__global__ void k_build_a1(const float* __restrict__ hid, const float* __restrict__ lf1,
                           bf16* __restrict__ hsb, bf16* __restrict__ A1) {
  int idx = blockIdx.x * 256 + threadIdx.x;  // < T*H
  int t = idx >> 11, h = idx & 2047;
  float x = hid[idx];
  hsb[idx] = (bf16)x;
  float xp;
  if ((t & (Sc - 1)) == 0)
    xp = lf1[(t >> 10) * Hc + h];
  else
    xp = hid[idx - Hc];
  size_t a = ((size_t)t << 12) + 2 * h;
  A1[a] = (bf16)xp;
  A1[a + 1] = (bf16)x;
}

// conv2 interleaved input A2[t][2c+tap] from o1
__global__ void k_build_a2(const bf16* __restrict__ o1, const float* __restrict__ lf2,
                           bf16* __restrict__ A2) {
  int idx = blockIdx.x * 256 + threadIdx.x;  // < T*1024
  int t = idx >> 10, c = idx & 1023;
  bf16 cur = o1[idx];
  bf16 prev;
  if ((t & (Sc - 1)) == 0)
    prev = (bf16)lf2[(t >> 10) * 1024 + c];
  else
    prev = o1[idx - 1024];
  size_t a = ((size_t)t << 11) + 2 * c;
  A2[a] = prev;
  A2[a + 1] = cur;
}

// lf = rmsnorm(o2 + hid) * g   (one block per row, 256 thr x 8 elems)
__global__ __launch_bounds__(256) void k_rmsnorm(const bf16* __restrict__ o2,
                                                 const float* __restrict__ hid,
                                                 const float* __restrict__ g,
                                                 bf16* __restrict__ lf) {
  int t = blockIdx.x, tid = threadIdx.x;
  size_t base = ((size_t)t << 11) + tid * 8;
  bf16x8 ov = *(const bf16x8*)&o2[base];
  const float* hp = &hid[base];
  float vals[8];
  float ss = 0.f;
#pragma unroll
  for (int i = 0; i < 8; ++i) {
    float x = (float)ov[i] + hp[i];
    vals[i] = x;
    ss += x * x;
  }
#pragma unroll
  for (int off = 1; off < 64; off <<= 1) ss += __shfl_xor(ss, off);
  __shared__ float red[4];
  if ((tid & 63) == 0) red[tid >> 6] = ss;
  __syncthreads();
  float tot = red[0] + red[1] + red[2] + red[3];
  float inv = rsqrtf(tot * (1.f / 2048.f) + 1e-6f);
  bf16x8 o;
#pragma unroll
  for (int i = 0; i < 8; ++i) o[i] = (bf16)(vals[i] * inv * g[tid * 8 + i]);
  *(bf16x8*)&lf[base] = o;
}

// RoPE on qk (T,NH,256) -> qr,kr laid out (B,NH,S,HD) bf16
__global__ void k_rope(const bf16* __restrict__ qk, const float* __restrict__ rot,
                       bf16* __restrict__ qr, bf16* __restrict__ kr) {
  int bid = blockIdx.x;  // T*NH
  int n = bid & 15, t = bid >> 4;
  int s = t & (Sc - 1), b = t >> 10;
  int tid = threadIdx.x;
  int isk = tid >> 7, d = tid & 127;
  const bf16* src = qk + ((size_t)t << 12) + n * 256 + isk * 128;
  float val = (float)src[d];
  float outv = val;
  if (d < 64) {
    float f = rot[s * 64 + d];
    float c = cosf(f), sn = sinf(f);
    float other = (float)src[d ^ 32];
    outv = (d < 32) ? (val * c - other * sn) : (val * c + other * sn);
  }
  bf16* dst = isk ? kr : qr;
  dst[((size_t)((b * 16 + n) * 1024 + s) << 7) + d] = (bf16)outv;
}

// v (T,P) -> vT (B,NH,HD,S), 32x32 LDS tile transpose
__global__ void k_vt(const bf16* __restrict__ v, bf16* __restrict__ vT) {
  __shared__ bf16 tile[32][33];
  int bid = blockIdx.x;
  int dt = bid & 3;          // HD/32
  int st = (bid >> 2) & 31;  // S/32
  int bn = bid >> 7;         // b*NH+n
  int b = bn >> 4, n = bn & 15;
  int tx = threadIdx.x & 31, ty = threadIdx.x >> 5;  // 32 x 8
#pragma unroll
  for (int i = 0; i < 4; ++i) {
    int s = st * 32 + ty + i * 8;
    int d = dt * 32 + tx;
    tile[ty + i * 8][tx] = v[(size_t)(b * 1024 + s) * 2048 + n * 128 + d];
  }
  __syncthreads();
#pragma unroll
  for (int i = 0; i < 4; ++i) {
    int d = dt * 32 + ty + i * 8;
    int s = st * 32 + tx;
    vT[((size_t)(bn * 128 + d)) * 1024 + s] = tile[tx][ty + i * 8];
  }
}

// ---------------------------------------------------------------------------
// causal flash attention v2: LDS-staged K/V, double-buffered global_load_lds,
// balanced q-tile pairs (pr, 15-pr), XCD-local (b,h) mapping.
// Block: 256 thr (4 waves x 16 q-rows), KV tile = 64. LDS 72KB -> 2 blk/CU.
// ---------------------------------------------------------------------------
__global__ __launch_bounds__(256, 2) void k_attn(const bf16* __restrict__ qr,
                                                 const bf16* __restrict__ kr,
                                                 const bf16* __restrict__ vT,
                                                 bf16* __restrict__ att) {
  __shared__ bf16 Ks[2][64 * 128];   // [tilebuf][krow][d]  (XOR-swizzled 16B groups)
  __shared__ bf16 Vs[2][128 * 64];   // [tilebuf][d][kcol]  (XOR-swizzled 16B groups)
  __shared__ bf16 plds[4][16 * 64];
  const int bid = blockIdx.x;
  // XCD-local mapping: all 8 pair-blocks of one (b,h) land on one XCD
  const int xcd = bid & 7, jj = bid >> 3;
  const int bn = xcd * 8 + (jj >> 3);
  const int pr = jj & 7;
  const int tid = threadIdx.x, w = tid >> 6, l = tid & 63;
  const int lr = l & 15, hi = l >> 4;
  const bf16* kb = kr + ((size_t)bn << 17);
  const bf16* vb = vT + ((size_t)bn << 17);
  const int b = bn >> 4, hh = bn & 15;
  const float scaling = 0.08838834764831845f;

  auto stage = [&](int buf, int kt) {
    // K tile: 64 rows x 256B; source col-group pre-swizzled (rule 21)
#pragma unroll
    for (int c = 0; c < 4; ++c) {
      int chunk = c * 256 + tid;
      int prow = chunk >> 4, pcg = chunk & 15;
      async16(kb + ((size_t)(kt * 64 + prow) << 7) + ((pcg ^ (prow & 7)) << 3),
              (char*)&Ks[buf][0] + chunk * 16);
    }
    // V tile: 128 rows x 128B
#pragma unroll
    for (int c = 0; c < 4; ++c) {
      int chunk = c * 256 + tid;
      int prow = chunk >> 3, pcg = chunk & 7;
      async16(vb + ((size_t)prow << 10) + kt * 64 + ((pcg ^ (prow & 7)) << 3),
              (char*)&Vs[buf][0] + chunk * 16);
    }
  };

#pragma unroll 1
  for (int phase = 0; phase < 2; ++phase) {
    const int qt = phase ? (15 - pr) : pr;
    const int qg0 = qt * 64 + w * 16;
    const bf16* qb = qr + ((size_t)(bn * 1024 + qg0) << 7);
    bf16x8 qf[4];
#pragma unroll
    for (int ks = 0; ks < 4; ++ks) qf[ks] = *(const bf16x8*)&qb[lr * 128 + ks * 32 + hi * 8];
    f32x4 oacc[8] = {};
    float mrow[4] = {-1e30f, -1e30f, -1e30f, -1e30f};
    float lrow[4] = {0.f, 0.f, 0.f, 0.f};
    const int nkb = qt + 1;  // block-uniform trip count

    stage(0, 0);
    __syncthreads();  // compiler drains vmcnt(0) before s_barrier

    for (int kbt = 0; kbt < nkb; ++kbt) {
      const int cur = kbt & 1;
      if (kbt + 1 < nkb) stage(cur ^ 1, kbt + 1);  // prefetch next tile (async)

      // ---- QK^T from LDS (swizzled reads) ----
      f32x4 sacc[4] = {};
#pragma unroll
      for (int n = 0; n < 4; ++n) {
        const int krow = n * 16 + lr;
#pragma unroll
        for (int ks = 0; ks < 4; ++ks) {
          bf16x8 kf = *(const bf16x8*)&Ks[cur][(krow << 7) + ((((ks << 2) | hi) ^ (krow & 7)) << 3)];
          sacc[n] = __builtin_amdgcn_mfma_f32_16x16x32_bf16(qf[ks], kf, sacc[n], 0, 0, 0);
        }
      }
      // ---- mask + online softmax ----
      const bool needmask = (kbt * 64 + 63 > qg0);
#pragma unroll
      for (int n = 0; n < 4; ++n) {
        int kg = kbt * 64 + n * 16 + lr;
#pragma unroll
        for (int j = 0; j < 4; ++j) {
          float sv = sacc[n][j] * scaling;
          if (needmask && kg > qg0 + hi * 4 + j) sv = -1e30f;
          sacc[n][j] = sv;
        }
      }
      float sf[4];
#pragma unroll
      for (int j = 0; j < 4; ++j) {
        float pm = fmaxf(fmaxf(sacc[0][j], sacc[1][j]), fmaxf(sacc[2][j], sacc[3][j]));
        pm = fmaxf(pm, __shfl_xor(pm, 1));
        pm = fmaxf(pm, __shfl_xor(pm, 2));
        pm = fmaxf(pm, __shfl_xor(pm, 4));
        pm = fmaxf(pm, __shfl_xor(pm, 8));
        float mn = fmaxf(mrow[j], pm);
        sf[j] = __expf(mrow[j] - mn);
        mrow[j] = mn;
      }
#pragma unroll
      for (int n = 0; n < 4; ++n)
#pragma unroll
        for (int j = 0; j < 4; ++j) sacc[n][j] = __expf(sacc[n][j] - mrow[j]);
#pragma unroll
      for (int j = 0; j < 4; ++j) {
        float ps = sacc[0][j] + sacc[1][j] + sacc[2][j] + sacc[3][j];
        ps += __shfl_xor(ps, 1);
        ps += __shfl_xor(ps, 2);
        ps += __shfl_xor(ps, 4);
        ps += __shfl_xor(ps, 8);
        lrow[j] = lrow[j] * sf[j] + ps;
      }
#pragma unroll
      for (int dt = 0; dt < 8; ++dt)
#pragma unroll
        for (int j = 0; j < 4; ++j) oacc[dt][j] *= sf[j];
      // ---- P -> LDS (per-wave), PV from LDS ----
#pragma unroll
      for (int n = 0; n < 4; ++n)
#pragma unroll
        for (int j = 0; j < 4; ++j)
          plds[w][(hi * 4 + j) * 64 + n * 16 + lr] = (bf16)sacc[n][j];
      asm volatile("s_waitcnt lgkmcnt(0)" ::: "memory");
#pragma unroll
      for (int ks2 = 0; ks2 < 2; ++ks2) {
        bf16x8 pf = *(const bf16x8*)&plds[w][lr * 64 + ks2 * 32 + hi * 8];
#pragma unroll
        for (int dt = 0; dt < 8; ++dt) {
          const int vrow = dt * 16 + lr;
          bf16x8 vf = *(const bf16x8*)&Vs[cur][(vrow << 6) + ((((ks2 << 2) | hi) ^ (lr & 7)) << 3)];
          oacc[dt] = __builtin_amdgcn_mfma_f32_16x16x32_bf16(pf, vf, oacc[dt], 0, 0, 0);
        }
      }
      __syncthreads();  // stage(kbt+1) drained + all reads of buf cur^1 done
    }

    // ---- writeout ----
#pragma unroll
    for (int j = 0; j < 4; ++j) {
      float inv = 1.f / lrow[j];
      int qg = qg0 + hi * 4 + j;
      size_t obase = ((size_t)(b * 1024 + qg) << 11) + hh * 128;
#pragma unroll
      for (int dt = 0; dt < 8; ++dt) att[obase + dt * 16 + lr] = (bf16)(oacc[dt][j] * inv);
    }
  }
}

// ---------------------------------------------------------------------------
// Workspace plan (120 MB total, sequential liveness — one stream, in-order):
//   W    0-16    weight slot (reused: Wv, c1w, c2w, Wqk(16MB), Wo)
//   S0  16-48    A1 (32MB)            -> qkb (32MB)
//   S1  48-64    hsb                  -> lfb      -> vT
//   S2  64-80    v                    -> att
//   S3  80-88    o1
//   S4  88-104   A2                   -> qr
//   S5 104-120   o2                   -> kr
// ---------------------------------------------------------------------------
extern "C" void kernel_launch(void* const* d_in, const int* in_sizes, int n_in,
                              void* d_out, int out_size, void* d_ws, size_t ws_size,
                              hipStream_t stream) {
  const float* hid = (const float*)d_in[1];
  const float* rot = (const float*)d_in[2];
  const float* lf1 = (const float*)d_in[3];
  const float* lf2 = (const float*)d_in[4];
  const float* Wqk = (const float*)d_in[5];
  const float* Wv  = (const float*)d_in[6];
  const float* Wo  = (const float*)d_in[7];
  const float* c1w = (const float*)d_in[8];
  const float* c1b = (const float*)d_in[9];
  const float* c2w = (const float*)d_in[10];
  const float* c2b = (const float*)d_in[11];
  const float* lng = (const float*)d_in[12];
  float* outp = (float*)d_out;
  char* ws = (char*)d_ws;

  const size_t MB = 1ull << 20;
  bf16* Wslot = (bf16*)(ws + 0 * MB);    // 16MB shared weight slot
  bf16* A1    = (bf16*)(ws + 16 * MB);   // 32MB
  bf16* qkb   = A1;                      // alias (A1 dead after conv1 gemm)
  bf16* hsb   = (bf16*)(ws + 48 * MB);   // 16MB
  bf16* lfb   = hsb;                     // alias (hsb dead after Wv gemm)
  bf16* vT    = hsb;                     // alias (lfb dead after Wqk gemm)
  bf16* v     = (bf16*)(ws + 64 * MB);   // 16MB
  bf16* att   = v;                       // alias (v dead after k_vt)
  bf16* o1    = (bf16*)(ws + 80 * MB);   // 8MB
  bf16* A2    = (bf16*)(ws + 88 * MB);   // 16MB
  bf16* qr    = A2;                      // alias (A2 dead after conv2 gemm)
  bf16* o2    = (bf16*)(ws + 104 * MB);  // 16MB
  bf16* kr    = o2;                      // alias (o2 dead after rmsnorm)

  auto f2b = [&](const float* in, bf16* out, int n) {
    int n4 = n / 4;
    k_f2b4<<<(n4 + 255) / 256, 256, 0, stream>>>(in, out, n4);
  };

  // 1. v = hs @ Wv.T
  f2b(Wv, Wslot, 2048 * 2048);
  k_build_a1<<<Tc * Hc / 256, 256, 0, stream>>>(hid, lf1, hsb, A1);
  gemm_bt<true><<<(Pc / 128) * (Tc / 128), 256, 0, stream>>>(hsb, Wslot, v, nullptr, Tc, Pc, Hc);

  // 2. conv1 (as GEMM over interleaved taps)
  f2b(c1w, Wslot, 1024 * 2048 * 2);
  gemm_bt<true><<<(1024 / 128) * (Tc / 128), 256, 0, stream>>>(A1, Wslot, o1, c1b, Tc, 1024, 4096);

  // 3. conv2
  k_build_a2<<<Tc * 1024 / 256, 256, 0, stream>>>(o1, lf2, A2);
  f2b(c2w, Wslot, 2048 * 1024 * 2);
  gemm_bt<true><<<(2048 / 128) * (Tc / 128), 256, 0, stream>>>(A2, Wslot, o2, c2b, Tc, 2048, 2048);

  // 4. residual + rmsnorm
  k_rmsnorm<<<Tc, 256, 0, stream>>>(o2, hid, lng, lfb);

  // 5. qk projection
  f2b(Wqk, Wslot, 4096 * 2048);
  gemm_bt<true><<<(4096 / 128) * (Tc / 128), 256, 0, stream>>>(lfb, Wslot, qkb, nullptr, Tc, 4096, 2048);

  // 6. rope, V transpose, attention (balanced pairs: 8 blocks per (b,h))
  k_rope<<<Tc * NHc, 256, 0, stream>>>(qkb, rot, qr, kr);
  k_vt<<<64 * 32 * 4, 256, 0, stream>>>(v, vT);
  k_attn<<<Bc * NHc * 8, 256, 0, stream>>>(qr, kr, vT, att);

  // 7. output projection (fp32 out)
  f2b(Wo, Wslot, 2048 * 2048);
  gemm_bt<false><<<(2048 / 128) * (Tc / 128), 256, 0, stream>>>(att, Wslot, outp, nullptr, Tc, 2048, 2048);
}

// Round 5
// 404.554 us; speedup vs baseline: 1.5638x; 1.0296x over previous
//
#include <hip/hip_runtime.h>

typedef __bf16 bf16;
typedef __bf16 bf16x8 __attribute__((ext_vector_type(8)));
typedef __bf16 bf16x4 __attribute__((ext_vector_type(4)));
typedef float f32x4 __attribute__((ext_vector_type(4)));

#define DEVI __device__ __forceinline__

// problem constants
constexpr int Bc = 4, Sc = 1024, Hc = 2048, NHc = 16, HDc = 128;
constexpr int Tc = Bc * Sc;   // 4096
constexpr int Pc = NHc * HDc; // 2048

DEVI void async16(const void* g, void* l) {
  __builtin_amdgcn_global_load_lds(
      (const __attribute__((address_space(1))) unsigned int*)g,
      (__attribute__((address_space(3))) unsigned int*)l, 16, 0, 0);
}

// ---------------------------------------------------------------------------
// Pipelined GEMM: C[m][n] = sum_k A[m][k] * W[n][k] (+ bias[n])
// A: M x K bf16 row-major, W: N x K bf16 row-major.
// 4-slot circular LDS pipeline at BK=32 (T3/T4): counted vmcnt(8) + raw
// s_barrier keeps 2 tiles of DMA in flight across barriers; stage(t+3) issued
// right after the barrier. XOR swizzle cg^=(row>>1)&3 on both global source
// and LDS read (rule 21). setprio(1) around the MFMA cluster (T5).
// Geometries: <2,2,4,4> = 128x128 tile, 256 thr; <2,4,8,4> = 256x256, 512 thr.
// ---------------------------------------------------------------------------
template <int WM, int WN, int MREP, int NREP, bool OUT_BF16>
__global__ __launch_bounds__(WM * WN * 64, 2) void gemm_pipe(
    const bf16* __restrict__ A, const bf16* __restrict__ W, void* __restrict__ Cout,
    const float* __restrict__ bias, int M, int N, int K) {
  constexpr int BM = WM * MREP * 16;
  constexpr int BN = WN * NREP * 16;
  constexpr int THREADS = WM * WN * 64;
  constexpr int ROWS = BM + BN;
  constexpr int CHA = BM * 4 / THREADS;  // A 16B-chunks per thread per stage
  constexpr int CHB = BN * 4 / THREADS;
  static_assert(CHA + CHB == 4, "vmcnt ledger assumes 4 loads/thread/stage");
  __shared__ bf16 lds[4][ROWS * 32];

  const int nbx = N / BN;
  const int nwg = (M / BM) * nbx;
  // bijective XCD chunking (all grids are multiples of 8)
  const int wgid = (blockIdx.x & 7) * (nwg >> 3) + (blockIdx.x >> 3);
  const int bx = wgid % nbx, by = wgid / nbx;
  const int m0 = by * BM, n0 = bx * BN;
  const int tid = threadIdx.x;
  const int w = tid >> 6, l = tid & 63;
  const int wm = w / WN, wn = w % WN;
  const int lr = l & 15;   // fragment row/col
  const int hi = l >> 4;   // k-group (8 elems each)

  auto stage = [&](int slot, int t) {
    const int k0 = t << 5;
#pragma unroll
    for (int c = 0; c < CHA; ++c) {
      const int ch = c * THREADS + tid;
      const int row = ch >> 2, cg = ch & 3;
      const int gc = (cg ^ ((row >> 1) & 3)) << 3;  // inverse-swizzled source col
      async16(A + (size_t)(m0 + row) * K + k0 + gc, (char*)&lds[slot][0] + ch * 16);
    }
#pragma unroll
    for (int c = 0; c < CHB; ++c) {
      const int ch = c * THREADS + tid;
      const int row = ch >> 2, cg = ch & 3;
      const int gc = (cg ^ ((row >> 1) & 3)) << 3;
      async16(W + (size_t)(n0 + row) * K + k0 + gc,
              (char*)&lds[slot][0] + (BM * 4 + ch) * 16);
    }
  };

  f32x4 acc[MREP][NREP] = {};
  const int nk = K >> 5;

  stage(0, 0);
  stage(1, 1);
  stage(2, 2);

  for (int t = 0; t < nk; ++t) {
    // counted vmcnt: tile t retired; tiles t+1,t+2 stay in flight (T4)
    if (t + 2 < nk)      asm volatile("s_waitcnt vmcnt(8)" ::: "memory");
    else if (t + 1 < nk) asm volatile("s_waitcnt vmcnt(4)" ::: "memory");
    else                 asm volatile("s_waitcnt vmcnt(0)" ::: "memory");
    __builtin_amdgcn_s_barrier();
    __builtin_amdgcn_sched_barrier(0);
    if (t + 3 < nk) stage((t + 3) & 3, t + 3);  // slot's old tile fully consumed

    const char* base = (const char*)&lds[t & 3][0];
    bf16x8 af[MREP], bfr[NREP];
#pragma unroll
    for (int mi = 0; mi < MREP; ++mi) {
      const int r = wm * (MREP * 16) + mi * 16 + lr;
      af[mi] = *(const bf16x8*)(base + r * 64 + ((hi ^ ((r >> 1) & 3)) << 4));
    }
#pragma unroll
    for (int ni = 0; ni < NREP; ++ni) {
      const int r = BM + wn * (NREP * 16) + ni * 16 + lr;
      bfr[ni] = *(const bf16x8*)(base + r * 64 + ((hi ^ ((r >> 1) & 3)) << 4));
    }
    __builtin_amdgcn_s_setprio(1);
#pragma unroll
    for (int mi = 0; mi < MREP; ++mi)
#pragma unroll
      for (int ni = 0; ni < NREP; ++ni)
        acc[mi][ni] = __builtin_amdgcn_mfma_f32_16x16x32_bf16(af[mi], bfr[ni], acc[mi][ni], 0, 0, 0);
    __builtin_amdgcn_s_setprio(0);
  }

#pragma unroll
  for (int ni = 0; ni < NREP; ++ni) {
    const int col = n0 + wn * (NREP * 16) + ni * 16 + lr;
    const float bv = bias ? bias[col] : 0.f;
#pragma unroll
    for (int mi = 0; mi < MREP; ++mi) {
#pragma unroll
      for (int j = 0; j < 4; ++j) {
        const int row = m0 + wm * (MREP * 16) + mi * 16 + (hi << 2) + j;
        const float vv = acc[mi][ni][j] + bv;
        if (OUT_BF16)
          ((bf16*)Cout)[(size_t)row * N + col] = (bf16)vv;
        else
          ((float*)Cout)[(size_t)row * N + col] = vv;
      }
    }
  }
}

// ---------------------------------------------------------------------------
// fp32 -> bf16 weight conversion (vectorized by 4)
// ---------------------------------------------------------------------------
__global__ void k_f2b4(const float* __restrict__ in, bf16* __restrict__ out, int n4) {
  int i = blockIdx.x * 256 + threadIdx.x;
  if (i >= n4) return;
  float4 v = ((const float4*)in)[i];
  bf16x4 o = {(bf16)v.x, (bf16)v.y, (bf16)v.z, (bf16)v.w};
  ((bf16x4*)out)[i] = o;
}

// hidden fp32 -> hsb bf16, and conv1 interleaved input A1[t][2h+tap]
__global__ void k_build_a1(const float* __restrict__ hid, const float* __restrict__ lf1,
                           bf16* __restrict__ hsb, bf16* __restrict__ A1) {
  int idx = blockIdx.x * 256 + threadIdx.x;  // < T*H
  int t = idx >> 11, h = idx & 2047;
  float x = hid[idx];
  hsb[idx] = (bf16)x;
  float xp;
  if ((t & (Sc - 1)) == 0)
    xp = lf1[(t >> 10) * Hc + h];
  else
    xp = hid[idx - Hc];
  size_t a = ((size_t)t << 12) + 2 * h;
  A1[a] = (bf16)xp;
  A1[a + 1] = (bf16)x;
}

// conv2 interleaved input A2[t][2c+tap] from o1
__global__ void k_build_a2(const bf16* __restrict__ o1, const float* __restrict__ lf2,
                           bf16* __restrict__ A2) {
  int idx = blockIdx.x * 256 + threadIdx.x;  // < T*1024
  int t = idx >> 10, c = idx & 1023;
  bf16 cur = o1[idx];
  bf16 prev;
  if ((t & (Sc - 1)) == 0)
    prev = (bf16)lf2[(t >> 10) * 1024 + c];
  else
    prev = o1[idx - 1024];
  size_t a = ((size_t)t << 11) + 2 * c;
  A2[a] = prev;
  A2[a + 1] = cur;
}

// lf = rmsnorm(o2 + hid) * g   (one block per row, 256 thr x 8 elems)
__global__ __launch_bounds__(256) void k_rmsnorm(const bf16* __restrict__ o2,
                                                 const float* __restrict__ hid,
                                                 const float* __restrict__ g,
                                                 bf16* __restrict__ lf) {
  int t = blockIdx.x, tid = threadIdx.x;
  size_t base = ((size_t)t << 11) + tid * 8;
  bf16x8 ov = *(const bf16x8*)&o2[base];
  const float* hp = &hid[base];
  float vals[8];
  float ss = 0.f;
#pragma unroll
  for (int i = 0; i < 8; ++i) {
    float x = (float)ov[i] + hp[i];
    vals[i] = x;
    ss += x * x;
  }
#pragma unroll
  for (int off = 1; off < 64; off <<= 1) ss += __shfl_xor(ss, off);
  __shared__ float red[4];
  if ((tid & 63) == 0) red[tid >> 6] = ss;
  __syncthreads();
  float tot = red[0] + red[1] + red[2] + red[3];
  float inv = rsqrtf(tot * (1.f / 2048.f) + 1e-6f);
  bf16x8 o;
#pragma unroll
  for (int i = 0; i < 8; ++i) o[i] = (bf16)(vals[i] * inv * g[tid * 8 + i]);
  *(bf16x8*)&lf[base] = o;
}

// RoPE on qk (T,NH,256) -> qr,kr laid out (B,NH,S,HD) bf16
__global__ void k_rope(const bf16* __restrict__ qk, const float* __restrict__ rot,
                       bf16* __restrict__ qr, bf16* __restrict__ kr) {
  int bid = blockIdx.x;  // T*NH
  int n = bid & 15, t = bid >> 4;
  int s = t & (Sc - 1), b = t >> 10;
  int tid = threadIdx.x;
  int isk = tid >> 7, d = tid & 127;
  const bf16* src = qk + ((size_t)t << 12) + n * 256 + isk * 128;
  float val = (float)src[d];
  float outv = val;
  if (d < 64) {
    float f = rot[s * 64 + d];
    float c = cosf(f), sn = sinf(f);
    float other = (float)src[d ^ 32];
    outv = (d < 32) ? (val * c - other * sn) : (val * c + other * sn);
  }
  bf16* dst = isk ? kr : qr;
  dst[((size_t)((b * 16 + n) * 1024 + s) << 7) + d] = (bf16)outv;
}

// v (T,P) -> vT (B,NH,HD,S), 32x32 LDS tile transpose
__global__ void k_vt(const bf16* __restrict__ v, bf16* __restrict__ vT) {
  __shared__ bf16 tile[32][33];
  int bid = blockIdx.x;
  int dt = bid & 3;          // HD/32
  int st = (bid >> 2) & 31;  // S/32
  int bn = bid >> 7;         // b*NH+n
  int b = bn >> 4, n = bn & 15;
  int tx = threadIdx.x & 31, ty = threadIdx.x >> 5;  // 32 x 8
#pragma unroll
  for (int i = 0; i < 4; ++i) {
    int s = st * 32 + ty + i * 8;
    int d = dt * 32 + tx;
    tile[ty + i * 8][tx] = v[(size_t)(b * 1024 + s) * 2048 + n * 128 + d];
  }
  __syncthreads();
#pragma unroll
  for (int i = 0; i < 4; ++i) {
    int d = dt * 32 + ty + i * 8;
    int s = st * 32 + tx;
    vT[((size_t)(bn * 128 + d)) * 1024 + s] = tile[tx][ty + i * 8];
  }
}

// ---------------------------------------------------------------------------
// causal flash attention v2: LDS-staged K/V, double-buffered global_load_lds,
// balanced q-tile pairs (pr, 15-pr), XCD-local (b,h) mapping.
// Block: 256 thr (4 waves x 16 q-rows), KV tile = 64. LDS 72KB -> 2 blk/CU.
// ---------------------------------------------------------------------------
__global__ __launch_bounds__(256, 2) void k_attn(const bf16* __restrict__ qr,
                                                 const bf16* __restrict__ kr,
                                                 const bf16* __restrict__ vT,
                                                 bf16* __restrict__ att) {
  __shared__ bf16 Ks[2][64 * 128];   // [tilebuf][krow][d]  (XOR-swizzled 16B groups)
  __shared__ bf16 Vs[2][128 * 64];   // [tilebuf][d][kcol]  (XOR-swizzled 16B groups)
  __shared__ bf16 plds[4][16 * 64];
  const int bid = blockIdx.x;
  // XCD-local mapping: all 8 pair-blocks of one (b,h) land on one XCD
  const int xcd = bid & 7, jj = bid >> 3;
  const int bn = xcd * 8 + (jj >> 3);
  const int pr = jj & 7;
  const int tid = threadIdx.x, w = tid >> 6, l = tid & 63;
  const int lr = l & 15, hi = l >> 4;
  const bf16* kb = kr + ((size_t)bn << 17);
  const bf16* vb = vT + ((size_t)bn << 17);
  const int b = bn >> 4, hh = bn & 15;
  const float scaling = 0.08838834764831845f;

  auto stage = [&](int buf, int kt) {
    // K tile: 64 rows x 256B; source col-group pre-swizzled (rule 21)
#pragma unroll
    for (int c = 0; c < 4; ++c) {
      int chunk = c * 256 + tid;
      int prow = chunk >> 4, pcg = chunk & 15;
      async16(kb + ((size_t)(kt * 64 + prow) << 7) + ((pcg ^ (prow & 7)) << 3),
              (char*)&Ks[buf][0] + chunk * 16);
    }
    // V tile: 128 rows x 128B
#pragma unroll
    for (int c = 0; c < 4; ++c) {
      int chunk = c * 256 + tid;
      int prow = chunk >> 3, pcg = chunk & 7;
      async16(vb + ((size_t)prow << 10) + kt * 64 + ((pcg ^ (prow & 7)) << 3),
              (char*)&Vs[buf][0] + chunk * 16);
    }
  };

#pragma unroll 1
  for (int phase = 0; phase < 2; ++phase) {
    const int qt = phase ? (15 - pr) : pr;
    const int qg0 = qt * 64 + w * 16;
    const bf16* qb = qr + ((size_t)(bn * 1024 + qg0) << 7);
    bf16x8 qf[4];
#pragma unroll
    for (int ks = 0; ks < 4; ++ks) qf[ks] = *(const bf16x8*)&qb[lr * 128 + ks * 32 + hi * 8];
    f32x4 oacc[8] = {};
    float mrow[4] = {-1e30f, -1e30f, -1e30f, -1e30f};
    float lrow[4] = {0.f, 0.f, 0.f, 0.f};
    const int nkb = qt + 1;  // block-uniform trip count

    stage(0, 0);
    __syncthreads();  // compiler drains vmcnt(0) before s_barrier

    for (int kbt = 0; kbt < nkb; ++kbt) {
      const int cur = kbt & 1;
      if (kbt + 1 < nkb) stage(cur ^ 1, kbt + 1);  // prefetch next tile (async)

      // ---- QK^T from LDS (swizzled reads) ----
      f32x4 sacc[4] = {};
#pragma unroll
      for (int n = 0; n < 4; ++n) {
        const int krow = n * 16 + lr;
#pragma unroll
        for (int ks = 0; ks < 4; ++ks) {
          bf16x8 kf = *(const bf16x8*)&Ks[cur][(krow << 7) + ((((ks << 2) | hi) ^ (krow & 7)) << 3)];
          sacc[n] = __builtin_amdgcn_mfma_f32_16x16x32_bf16(qf[ks], kf, sacc[n], 0, 0, 0);
        }
      }
      // ---- mask + online softmax ----
      const bool needmask = (kbt * 64 + 63 > qg0);
#pragma unroll
      for (int n = 0; n < 4; ++n) {
        int kg = kbt * 64 + n * 16 + lr;
#pragma unroll
        for (int j = 0; j < 4; ++j) {
          float sv = sacc[n][j] * scaling;
          if (needmask && kg > qg0 + hi * 4 + j) sv = -1e30f;
          sacc[n][j] = sv;
        }
      }
      float sf[4];
#pragma unroll
      for (int j = 0; j < 4; ++j) {
        float pm = fmaxf(fmaxf(sacc[0][j], sacc[1][j]), fmaxf(sacc[2][j], sacc[3][j]));
        pm = fmaxf(pm, __shfl_xor(pm, 1));
        pm = fmaxf(pm, __shfl_xor(pm, 2));
        pm = fmaxf(pm, __shfl_xor(pm, 4));
        pm = fmaxf(pm, __shfl_xor(pm, 8));
        float mn = fmaxf(mrow[j], pm);
        sf[j] = __expf(mrow[j] - mn);
        mrow[j] = mn;
      }
#pragma unroll
      for (int n = 0; n < 4; ++n)
#pragma unroll
        for (int j = 0; j < 4; ++j) sacc[n][j] = __expf(sacc[n][j] - mrow[j]);
#pragma unroll
      for (int j = 0; j < 4; ++j) {
        float ps = sacc[0][j] + sacc[1][j] + sacc[2][j] + sacc[3][j];
        ps += __shfl_xor(ps, 1);
        ps += __shfl_xor(ps, 2);
        ps += __shfl_xor(ps, 4);
        ps += __shfl_xor(ps, 8);
        lrow[j] = lrow[j] * sf[j] + ps;
      }
#pragma unroll
      for (int dt = 0; dt < 8; ++dt)
#pragma unroll
        for (int j = 0; j < 4; ++j) oacc[dt][j] *= sf[j];
      // ---- P -> LDS (per-wave), PV from LDS ----
#pragma unroll
      for (int n = 0; n < 4; ++n)
#pragma unroll
        for (int j = 0; j < 4; ++j)
          plds[w][(hi * 4 + j) * 64 + n * 16 + lr] = (bf16)sacc[n][j];
      asm volatile("s_waitcnt lgkmcnt(0)" ::: "memory");
#pragma unroll
      for (int ks2 = 0; ks2 < 2; ++ks2) {
        bf16x8 pf = *(const bf16x8*)&plds[w][lr * 64 + ks2 * 32 + hi * 8];
#pragma unroll
        for (int dt = 0; dt < 8; ++dt) {
          const int vrow = dt * 16 + lr;
          bf16x8 vf = *(const bf16x8*)&Vs[cur][(vrow << 6) + ((((ks2 << 2) | hi) ^ (lr & 7)) << 3)];
          oacc[dt] = __builtin_amdgcn_mfma_f32_16x16x32_bf16(pf, vf, oacc[dt], 0, 0, 0);
        }
      }
      __syncthreads();  // stage(kbt+1) drained + all reads of buf cur^1 done
    }

    // ---- writeout ----
#pragma unroll
    for (int j = 0; j < 4; ++j) {
      float inv = 1.f / lrow[j];
      int qg = qg0 + hi * 4 + j;
      size_t obase = ((size_t)(b * 1024 + qg) << 11) + hh * 128;
#pragma unroll
      for (int dt = 0; dt < 8; ++dt) att[obase + dt * 16 + lr] = (bf16)(oacc[dt][j] * inv);
    }
  }
}

// ---------------------------------------------------------------------------
// Workspace plan (120 MB total, sequential liveness — one stream, in-order):
//   W    0-16    weight slot (reused: Wv, c1w, c2w, Wqk(16MB), Wo)
//   S0  16-48    A1 (32MB)            -> qkb (32MB)
//   S1  48-64    hsb                  -> lfb      -> vT
//   S2  64-80    v                    -> att
//   S3  80-88    o1
//   S4  88-104   A2                   -> qr
//   S5 104-120   o2                   -> kr
// ---------------------------------------------------------------------------
extern "C" void kernel_launch(void* const* d_in, const int* in_sizes, int n_in,
                              void* d_out, int out_size, void* d_ws, size_t ws_size,
                              hipStream_t stream) {
  const float* hid = (const float*)d_in[1];
  const float* rot = (const float*)d_in[2];
  const float* lf1 = (const float*)d_in[3];
  const float* lf2 = (const float*)d_in[4];
  const float* Wqk = (const float*)d_in[5];
  const float* Wv  = (const float*)d_in[6];
  const float* Wo  = (const float*)d_in[7];
  const float* c1w = (const float*)d_in[8];
  const float* c1b = (const float*)d_in[9];
  const float* c2w = (const float*)d_in[10];
  const float* c2b = (const float*)d_in[11];
  const float* lng = (const float*)d_in[12];
  float* outp = (float*)d_out;
  char* ws = (char*)d_ws;

  const size_t MB = 1ull << 20;
  bf16* Wslot = (bf16*)(ws + 0 * MB);    // 16MB shared weight slot
  bf16* A1    = (bf16*)(ws + 16 * MB);   // 32MB
  bf16* qkb   = A1;                      // alias (A1 dead after conv1 gemm)
  bf16* hsb   = (bf16*)(ws + 48 * MB);   // 16MB
  bf16* lfb   = hsb;                     // alias (hsb dead after Wv gemm)
  bf16* vT    = hsb;                     // alias (lfb dead after Wqk gemm)
  bf16* v     = (bf16*)(ws + 64 * MB);   // 16MB
  bf16* att   = v;                       // alias (v dead after k_vt)
  bf16* o1    = (bf16*)(ws + 80 * MB);   // 8MB
  bf16* A2    = (bf16*)(ws + 88 * MB);   // 16MB
  bf16* qr    = A2;                      // alias (A2 dead after conv2 gemm)
  bf16* o2    = (bf16*)(ws + 104 * MB);  // 16MB
  bf16* kr    = o2;                      // alias (o2 dead after rmsnorm)

  auto f2b = [&](const float* in, bf16* out, int n) {
    int n4 = n / 4;
    k_f2b4<<<(n4 + 255) / 256, 256, 0, stream>>>(in, out, n4);
  };

  // 1. v = hs @ Wv.T   (M=4096,N=2048,K=2048; 128^2 tiles -> 512 blocks)
  f2b(Wv, Wslot, 2048 * 2048);
  k_build_a1<<<Tc * Hc / 256, 256, 0, stream>>>(hid, lf1, hsb, A1);
  gemm_pipe<2, 2, 4, 4, true><<<512, 256, 0, stream>>>(hsb, Wslot, v, nullptr, Tc, Pc, Hc);

  // 2. conv1 (as GEMM; M=4096,N=1024,K=4096; 256 blocks)
  f2b(c1w, Wslot, 1024 * 2048 * 2);
  gemm_pipe<2, 2, 4, 4, true><<<256, 256, 0, stream>>>(A1, Wslot, o1, c1b, Tc, 1024, 4096);

  // 3. conv2 (M=4096,N=2048,K=2048; 512 blocks)
  k_build_a2<<<Tc * 1024 / 256, 256, 0, stream>>>(o1, lf2, A2);
  f2b(c2w, Wslot, 2048 * 1024 * 2);
  gemm_pipe<2, 2, 4, 4, true><<<512, 256, 0, stream>>>(A2, Wslot, o2, c2b, Tc, 2048, 2048);

  // 4. residual + rmsnorm
  k_rmsnorm<<<Tc, 256, 0, stream>>>(o2, hid, lng, lfb);

  // 5. qk projection (M=4096,N=4096,K=2048; 256^2 tiles -> 256 blocks, 1/CU)
  f2b(Wqk, Wslot, 4096 * 2048);
  gemm_pipe<2, 4, 8, 4, true><<<256, 512, 0, stream>>>(lfb, Wslot, qkb, nullptr, Tc, 4096, Hc);

  // 6. rope, V transpose, attention (balanced pairs: 8 blocks per (b,h))
  k_rope<<<Tc * NHc, 256, 0, stream>>>(qkb, rot, qr, kr);
  k_vt<<<64 * 32 * 4, 256, 0, stream>>>(v, vT);
  k_attn<<<Bc * NHc * 8, 256, 0, stream>>>(qr, kr, vT, att);

  // 7. output projection (fp32 out; 512 blocks)
  f2b(Wo, Wslot, 2048 * 2048);
  gemm_pipe<2, 2, 4, 4, false><<<512, 256, 0, stream>>>(att, Wslot, outp, nullptr, Tc, 2048, 2048);
}

// Round 6
// 401.923 us; speedup vs baseline: 1.5741x; 1.0065x over previous
//
#include <hip/hip_runtime.h>

typedef __bf16 bf16;
typedef __bf16 bf16x8 __attribute__((ext_vector_type(8)));
typedef __bf16 bf16x4 __attribute__((ext_vector_type(4)));
typedef float f32x4 __attribute__((ext_vector_type(4)));

#define DEVI __device__ __forceinline__

// problem constants
constexpr int Bc = 4, Sc = 1024, Hc = 2048, NHc = 16, HDc = 128;
constexpr int Tc = Bc * Sc;   // 4096
constexpr int Pc = NHc * HDc; // 2048

DEVI void async16(const void* g, void* l) {
  __builtin_amdgcn_global_load_lds(
      (const __attribute__((address_space(1))) unsigned int*)g,
      (__attribute__((address_space(3))) unsigned int*)l, 16, 0, 0);
}

// ---------------------------------------------------------------------------
// Pipelined GEMM: C[m][n] = sum_k A[m][k] * W[n][k] (+ bias[n])
// A: M x K bf16 row-major, W: N x K bf16 row-major.
// 4-slot circular LDS pipeline at BK=32 (T3/T4) + one-step register
// read-ahead: step t holds tile t's fragments in regs (read at step t-1),
// MFMAs issue right after the barrier while this step's ds_reads (tile t+1)
// fly underneath them. vmcnt ledger: prologue 8, steady 4, drain 0.
// XOR swizzle cg^=(row>>1)&3 on both global source and LDS read (rule 21).
// Geometries: <2,2,4,4> = 128x128 tile, 256 thr; <2,4,8,4> = 256x256, 512 thr.
// ---------------------------------------------------------------------------
template <int WM, int WN, int MREP, int NREP, bool OUT_BF16>
__global__ __launch_bounds__(WM * WN * 64, 2) void gemm_pipe(
    const bf16* __restrict__ A, const bf16* __restrict__ W, void* __restrict__ Cout,
    const float* __restrict__ bias, int M, int N, int K) {
  constexpr int BM = WM * MREP * 16;
  constexpr int BN = WN * NREP * 16;
  constexpr int THREADS = WM * WN * 64;
  constexpr int ROWS = BM + BN;
  constexpr int CHA = BM * 4 / THREADS;  // A 16B-chunks per thread per stage
  constexpr int CHB = BN * 4 / THREADS;
  static_assert(CHA + CHB == 4, "vmcnt ledger assumes 4 loads/thread/stage");
  __shared__ bf16 lds[4][ROWS * 32];

  const int nbx = N / BN;
  const int nwg = (M / BM) * nbx;
  // bijective XCD chunking (all grids are multiples of 8)
  const int wgid = (blockIdx.x & 7) * (nwg >> 3) + (blockIdx.x >> 3);
  const int bx = wgid % nbx, by = wgid / nbx;
  const int m0 = by * BM, n0 = bx * BN;
  const int tid = threadIdx.x;
  const int w = tid >> 6, l = tid & 63;
  const int wm = w / WN, wn = w % WN;
  const int lr = l & 15;   // fragment row/col
  const int hi = l >> 4;   // k-group (8 elems each)

  auto stage = [&](int slot, int t) {
    const int k0 = t << 5;
#pragma unroll
    for (int c = 0; c < CHA; ++c) {
      const int ch = c * THREADS + tid;
      const int row = ch >> 2, cg = ch & 3;
      const int gc = (cg ^ ((row >> 1) & 3)) << 3;  // inverse-swizzled source col
      async16(A + (size_t)(m0 + row) * K + k0 + gc, (char*)&lds[slot][0] + ch * 16);
    }
#pragma unroll
    for (int c = 0; c < CHB; ++c) {
      const int ch = c * THREADS + tid;
      const int row = ch >> 2, cg = ch & 3;
      const int gc = (cg ^ ((row >> 1) & 3)) << 3;
      async16(W + (size_t)(n0 + row) * K + k0 + gc,
              (char*)&lds[slot][0] + (BM * 4 + ch) * 16);
    }
  };

  f32x4 acc[MREP][NREP] = {};
  const int nk = K >> 5;  // all K are multiples of 64 -> nk even

  stage(0, 0);
  stage(1, 1);
  stage(2, 2);
  asm volatile("s_waitcnt vmcnt(8)" ::: "memory");  // tile 0 resident
  __builtin_amdgcn_s_barrier();
  __builtin_amdgcn_sched_barrier(0);

  bf16x8 fAc[MREP], fBc[NREP], fAn[MREP], fBn[NREP];
  {
    const char* nb = (const char*)&lds[0][0];
#pragma unroll
    for (int mi = 0; mi < MREP; ++mi) {
      const int r = wm * (MREP * 16) + mi * 16 + lr;
      fAc[mi] = *(const bf16x8*)(nb + r * 64 + ((hi ^ ((r >> 1) & 3)) << 4));
    }
#pragma unroll
    for (int ni = 0; ni < NREP; ++ni) {
      const int r = BM + wn * (NREP * 16) + ni * 16 + lr;
      fBc[ni] = *(const bf16x8*)(nb + r * 64 + ((hi ^ ((r >> 1) & 3)) << 4));
    }
  }

#define GSTEP(T_, CA, CB, NA, NB)                                              \
  do {                                                                         \
    if ((T_) + 2 < nk) asm volatile("s_waitcnt vmcnt(4)" ::: "memory");        \
    else               asm volatile("s_waitcnt vmcnt(0)" ::: "memory");        \
    __builtin_amdgcn_s_barrier();                                              \
    __builtin_amdgcn_sched_barrier(0);                                         \
    if ((T_) + 3 < nk) stage(((T_) + 3) & 3, (T_) + 3);                        \
    if ((T_) + 1 < nk) {                                                       \
      const char* nb = (const char*)&lds[((T_) + 1) & 3][0];                   \
      _Pragma("unroll") for (int mi = 0; mi < MREP; ++mi) {                    \
        const int r = wm * (MREP * 16) + mi * 16 + lr;                         \
        NA[mi] = *(const bf16x8*)(nb + r * 64 + ((hi ^ ((r >> 1) & 3)) << 4)); \
      }                                                                        \
      _Pragma("unroll") for (int ni = 0; ni < NREP; ++ni) {                    \
        const int r = BM + wn * (NREP * 16) + ni * 16 + lr;                    \
        NB[ni] = *(const bf16x8*)(nb + r * 64 + ((hi ^ ((r >> 1) & 3)) << 4)); \
      }                                                                        \
    }                                                                          \
    __builtin_amdgcn_s_setprio(1);                                             \
    _Pragma("unroll") for (int mi = 0; mi < MREP; ++mi)                        \
      _Pragma("unroll") for (int ni = 0; ni < NREP; ++ni)                      \
        acc[mi][ni] =                                                          \
            __builtin_amdgcn_mfma_f32_16x16x32_bf16(CA[mi], CB[ni], acc[mi][ni], 0, 0, 0); \
    __builtin_amdgcn_s_setprio(0);                                             \
  } while (0)

  for (int t = 0; t < nk; t += 2) {
    GSTEP(t, fAc, fBc, fAn, fBn);
    GSTEP(t + 1, fAn, fBn, fAc, fBc);
  }
#undef GSTEP

#pragma unroll
  for (int ni = 0; ni < NREP; ++ni) {
    const int col = n0 + wn * (NREP * 16) + ni * 16 + lr;
    const float bv = bias ? bias[col] : 0.f;
#pragma unroll
    for (int mi = 0; mi < MREP; ++mi) {
#pragma unroll
      for (int j = 0; j < 4; ++j) {
        const int row = m0 + wm * (MREP * 16) + mi * 16 + (hi << 2) + j;
        const float vv = acc[mi][ni][j] + bv;
        if (OUT_BF16)
          ((bf16*)Cout)[(size_t)row * N + col] = (bf16)vv;
        else
          ((float*)Cout)[(size_t)row * N + col] = vv;
      }
    }
  }
}

// ---------------------------------------------------------------------------
// fp32 -> bf16 weight conversion (vectorized by 4)
// ---------------------------------------------------------------------------
__global__ void k_f2b4(const float* __restrict__ in, bf16* __restrict__ out, int n4) {
  int i = blockIdx.x * 256 + threadIdx.x;
  if (i >= n4) return;
  float4 v = ((const float4*)in)[i];
  bf16x4 o = {(bf16)v.x, (bf16)v.y, (bf16)v.z, (bf16)v.w};
  ((bf16x4*)out)[i] = o;
}

// hidden fp32 -> hsb bf16, and conv1 interleaved input A1[t][2h+tap]
__global__ void k_build_a1(const float* __restrict__ hid, const float* __restrict__ lf1,
                           bf16* __restrict__ hsb, bf16* __restrict__ A1) {
  int idx = blockIdx.x * 256 + threadIdx.x;  // < T*H
  int t = idx >> 11, h = idx & 2047;
  float x = hid[idx];
  hsb[idx] = (bf16)x;
  float xp;
  if ((t & (Sc - 1)) == 0)
    xp = lf1[(t >> 10) * Hc + h];
  else
    xp = hid[idx - Hc];
  size_t a = ((size_t)t << 12) + 2 * h;
  A1[a] = (bf16)xp;
  A1[a + 1] = (bf16)x;
}

// conv2 interleaved input A2[t][2c+tap] from o1
__global__ void k_build_a2(const bf16* __restrict__ o1, const float* __restrict__ lf2,
                           bf16* __restrict__ A2) {
  int idx = blockIdx.x * 256 + threadIdx.x;  // < T*1024
  int t = idx >> 10, c = idx & 1023;
  bf16 cur = o1[idx];
  bf16 prev;
  if ((t & (Sc - 1)) == 0)
    prev = (bf16)lf2[(t >> 10) * 1024 + c];
  else
    prev = o1[idx - 1024];
  size_t a = ((size_t)t << 11) + 2 * c;
  A2[a] = prev;
  A2[a + 1] = cur;
}

// lf = rmsnorm(o2 + hid) * g   (one block per row, 256 thr x 8 elems)
__global__ __launch_bounds__(256) void k_rmsnorm(const bf16* __restrict__ o2,
                                                 const float* __restrict__ hid,
                                                 const float* __restrict__ g,
                                                 bf16* __restrict__ lf) {
  int t = blockIdx.x, tid = threadIdx.x;
  size_t base = ((size_t)t << 11) + tid * 8;
  bf16x8 ov = *(const bf16x8*)&o2[base];
  const float* hp = &hid[base];
  float vals[8];
  float ss = 0.f;
#pragma unroll
  for (int i = 0; i < 8; ++i) {
    float x = (float)ov[i] + hp[i];
    vals[i] = x;
    ss += x * x;
  }
#pragma unroll
  for (int off = 1; off < 64; off <<= 1) ss += __shfl_xor(ss, off);
  __shared__ float red[4];
  if ((tid & 63) == 0) red[tid >> 6] = ss;
  __syncthreads();
  float tot = red[0] + red[1] + red[2] + red[3];
  float inv = rsqrtf(tot * (1.f / 2048.f) + 1e-6f);
  bf16x8 o;
#pragma unroll
  for (int i = 0; i < 8; ++i) o[i] = (bf16)(vals[i] * inv * g[tid * 8 + i]);
  *(bf16x8*)&lf[base] = o;
}

// RoPE on qk (T,NH,256) -> qr,kr laid out (B,NH,S,HD) bf16
__global__ void k_rope(const bf16* __restrict__ qk, const float* __restrict__ rot,
                       bf16* __restrict__ qr, bf16* __restrict__ kr) {
  int bid = blockIdx.x;  // T*NH
  int n = bid & 15, t = bid >> 4;
  int s = t & (Sc - 1), b = t >> 10;
  int tid = threadIdx.x;
  int isk = tid >> 7, d = tid & 127;
  const bf16* src = qk + ((size_t)t << 12) + n * 256 + isk * 128;
  float val = (float)src[d];
  float outv = val;
  if (d < 64) {
    float f = rot[s * 64 + d];
    float c = cosf(f), sn = sinf(f);
    float other = (float)src[d ^ 32];
    outv = (d < 32) ? (val * c - other * sn) : (val * c + other * sn);
  }
  bf16* dst = isk ? kr : qr;
  dst[((size_t)((b * 16 + n) * 1024 + s) << 7) + d] = (bf16)outv;
}

// v (T,P) -> vT (B,NH,HD,S), 32x32 LDS tile transpose
__global__ void k_vt(const bf16* __restrict__ v, bf16* __restrict__ vT) {
  __shared__ bf16 tile[32][33];
  int bid = blockIdx.x;
  int dt = bid & 3;          // HD/32
  int st = (bid >> 2) & 31;  // S/32
  int bn = bid >> 7;         // b*NH+n
  int b = bn >> 4, n = bn & 15;
  int tx = threadIdx.x & 31, ty = threadIdx.x >> 5;  // 32 x 8
#pragma unroll
  for (int i = 0; i < 4; ++i) {
    int s = st * 32 + ty + i * 8;
    int d = dt * 32 + tx;
    tile[ty + i * 8][tx] = v[(size_t)(b * 1024 + s) * 2048 + n * 128 + d];
  }
  __syncthreads();
#pragma unroll
  for (int i = 0; i < 4; ++i) {
    int d = dt * 32 + ty + i * 8;
    int s = st * 32 + tx;
    vT[((size_t)(bn * 128 + d)) * 1024 + s] = tile[tx][ty + i * 8];
  }
}

// ---------------------------------------------------------------------------
// causal flash attention v2: LDS-staged K/V, double-buffered global_load_lds,
// balanced q-tile pairs (pr, 15-pr), XCD-local (b,h) mapping.
// Block: 256 thr (4 waves x 16 q-rows), KV tile = 64. LDS 72KB -> 2 blk/CU.
// ---------------------------------------------------------------------------
__global__ __launch_bounds__(256, 2) void k_attn(const bf16* __restrict__ qr,
                                                 const bf16* __restrict__ kr,
                                                 const bf16* __restrict__ vT,
                                                 bf16* __restrict__ att) {
  __shared__ bf16 Ks[2][64 * 128];   // [tilebuf][krow][d]  (XOR-swizzled 16B groups)
  __shared__ bf16 Vs[2][128 * 64];   // [tilebuf][d][kcol]  (XOR-swizzled 16B groups)
  __shared__ bf16 plds[4][16 * 64];
  const int bid = blockIdx.x;
  // XCD-local mapping: all 8 pair-blocks of one (b,h) land on one XCD
  const int xcd = bid & 7, jj = bid >> 3;
  const int bn = xcd * 8 + (jj >> 3);
  const int pr = jj & 7;
  const int tid = threadIdx.x, w = tid >> 6, l = tid & 63;
  const int lr = l & 15, hi = l >> 4;
  const bf16* kb = kr + ((size_t)bn << 17);
  const bf16* vb = vT + ((size_t)bn << 17);
  const int b = bn >> 4, hh = bn & 15;
  const float scaling = 0.08838834764831845f;

  auto stage = [&](int buf, int kt) {
    // K tile: 64 rows x 256B; source col-group pre-swizzled (rule 21)
#pragma unroll
    for (int c = 0; c < 4; ++c) {
      int chunk = c * 256 + tid;
      int prow = chunk >> 4, pcg = chunk & 15;
      async16(kb + ((size_t)(kt * 64 + prow) << 7) + ((pcg ^ (prow & 7)) << 3),
              (char*)&Ks[buf][0] + chunk * 16);
    }
    // V tile: 128 rows x 128B
#pragma unroll
    for (int c = 0; c < 4; ++c) {
      int chunk = c * 256 + tid;
      int prow = chunk >> 3, pcg = chunk & 7;
      async16(vb + ((size_t)prow << 10) + kt * 64 + ((pcg ^ (prow & 7)) << 3),
              (char*)&Vs[buf][0] + chunk * 16);
    }
  };

#pragma unroll 1
  for (int phase = 0; phase < 2; ++phase) {
    const int qt = phase ? (15 - pr) : pr;
    const int qg0 = qt * 64 + w * 16;
    const bf16* qb = qr + ((size_t)(bn * 1024 + qg0) << 7);
    bf16x8 qf[4];
#pragma unroll
    for (int ks = 0; ks < 4; ++ks) qf[ks] = *(const bf16x8*)&qb[lr * 128 + ks * 32 + hi * 8];
    f32x4 oacc[8] = {};
    float mrow[4] = {-1e30f, -1e30f, -1e30f, -1e30f};
    float lrow[4] = {0.f, 0.f, 0.f, 0.f};
    const int nkb = qt + 1;  // block-uniform trip count

    stage(0, 0);
    __syncthreads();  // compiler drains vmcnt(0) before s_barrier

    for (int kbt = 0; kbt < nkb; ++kbt) {
      const int cur = kbt & 1;
      if (kbt + 1 < nkb) stage(cur ^ 1, kbt + 1);  // prefetch next tile (async)

      // ---- QK^T from LDS (swizzled reads) ----
      f32x4 sacc[4] = {};
#pragma unroll
      for (int n = 0; n < 4; ++n) {
        const int krow = n * 16 + lr;
#pragma unroll
        for (int ks = 0; ks < 4; ++ks) {
          bf16x8 kf = *(const bf16x8*)&Ks[cur][(krow << 7) + ((((ks << 2) | hi) ^ (krow & 7)) << 3)];
          sacc[n] = __builtin_amdgcn_mfma_f32_16x16x32_bf16(qf[ks], kf, sacc[n], 0, 0, 0);
        }
      }
      // ---- mask + online softmax ----
      const bool needmask = (kbt * 64 + 63 > qg0);
#pragma unroll
      for (int n = 0; n < 4; ++n) {
        int kg = kbt * 64 + n * 16 + lr;
#pragma unroll
        for (int j = 0; j < 4; ++j) {
          float sv = sacc[n][j] * scaling;
          if (needmask && kg > qg0 + hi * 4 + j) sv = -1e30f;
          sacc[n][j] = sv;
        }
      }
      float sf[4];
#pragma unroll
      for (int j = 0; j < 4; ++j) {
        float pm = fmaxf(fmaxf(sacc[0][j], sacc[1][j]), fmaxf(sacc[2][j], sacc[3][j]));
        pm = fmaxf(pm, __shfl_xor(pm, 1));
        pm = fmaxf(pm, __shfl_xor(pm, 2));
        pm = fmaxf(pm, __shfl_xor(pm, 4));
        pm = fmaxf(pm, __shfl_xor(pm, 8));
        float mn = fmaxf(mrow[j], pm);
        sf[j] = __expf(mrow[j] - mn);
        mrow[j] = mn;
      }
#pragma unroll
      for (int n = 0; n < 4; ++n)
#pragma unroll
        for (int j = 0; j < 4; ++j) sacc[n][j] = __expf(sacc[n][j] - mrow[j]);
#pragma unroll
      for (int j = 0; j < 4; ++j) {
        float ps = sacc[0][j] + sacc[1][j] + sacc[2][j] + sacc[3][j];
        ps += __shfl_xor(ps, 1);
        ps += __shfl_xor(ps, 2);
        ps += __shfl_xor(ps, 4);
        ps += __shfl_xor(ps, 8);
        lrow[j] = lrow[j] * sf[j] + ps;
      }
#pragma unroll
      for (int dt = 0; dt < 8; ++dt)
#pragma unroll
        for (int j = 0; j < 4; ++j) oacc[dt][j] *= sf[j];
      // ---- P -> LDS (per-wave), PV from LDS ----
#pragma unroll
      for (int n = 0; n < 4; ++n)
#pragma unroll
        for (int j = 0; j < 4; ++j)
          plds[w][(hi * 4 + j) * 64 + n * 16 + lr] = (bf16)sacc[n][j];
      asm volatile("s_waitcnt lgkmcnt(0)" ::: "memory");
#pragma unroll
      for (int ks2 = 0; ks2 < 2; ++ks2) {
        bf16x8 pf = *(const bf16x8*)&plds[w][lr * 64 + ks2 * 32 + hi * 8];
#pragma unroll
        for (int dt = 0; dt < 8; ++dt) {
          const int vrow = dt * 16 + lr;
          bf16x8 vf = *(const bf16x8*)&Vs[cur][(vrow << 6) + ((((ks2 << 2) | hi) ^ (lr & 7)) << 3)];
          oacc[dt] = __builtin_amdgcn_mfma_f32_16x16x32_bf16(pf, vf, oacc[dt], 0, 0, 0);
        }
      }
      __syncthreads();  // stage(kbt+1) drained + all reads of buf cur^1 done
    }

    // ---- writeout ----
#pragma unroll
    for (int j = 0; j < 4; ++j) {
      float inv = 1.f / lrow[j];
      int qg = qg0 + hi * 4 + j;
      size_t obase = ((size_t)(b * 1024 + qg) << 11) + hh * 128;
#pragma unroll
      for (int dt = 0; dt < 8; ++dt) att[obase + dt * 16 + lr] = (bf16)(oacc[dt][j] * inv);
    }
  }
}

// ---------------------------------------------------------------------------
// Workspace plan (120 MB total, sequential liveness — one stream, in-order):
//   W    0-16    weight slot (reused: Wv, c1w, c2w, Wqk(16MB), Wo)
//   S0  16-48    A1 (32MB)            -> qkb (32MB)
//   S1  48-64    hsb                  -> lfb      -> vT
//   S2  64-80    v                    -> att
//   S3  80-88    o1
//   S4  88-104   A2                   -> qr
//   S5 104-120   o2                   -> kr
// ---------------------------------------------------------------------------
extern "C" void kernel_launch(void* const* d_in, const int* in_sizes, int n_in,
                              void* d_out, int out_size, void* d_ws, size_t ws_size,
                              hipStream_t stream) {
  const float* hid = (const float*)d_in[1];
  const float* rot = (const float*)d_in[2];
  const float* lf1 = (const float*)d_in[3];
  const float* lf2 = (const float*)d_in[4];
  const float* Wqk = (const float*)d_in[5];
  const float* Wv  = (const float*)d_in[6];
  const float* Wo  = (const float*)d_in[7];
  const float* c1w = (const float*)d_in[8];
  const float* c1b = (const float*)d_in[9];
  const float* c2w = (const float*)d_in[10];
  const float* c2b = (const float*)d_in[11];
  const float* lng = (const float*)d_in[12];
  float* outp = (float*)d_out;
  char* ws = (char*)d_ws;

  const size_t MB = 1ull << 20;
  bf16* Wslot = (bf16*)(ws + 0 * MB);    // 16MB shared weight slot
  bf16* A1    = (bf16*)(ws + 16 * MB);   // 32MB
  bf16* qkb   = A1;                      // alias (A1 dead after conv1 gemm)
  bf16* hsb   = (bf16*)(ws + 48 * MB);   // 16MB
  bf16* lfb   = hsb;                     // alias (hsb dead after Wv gemm)
  bf16* vT    = hsb;                     // alias (lfb dead after Wqk gemm)
  bf16* v     = (bf16*)(ws + 64 * MB);   // 16MB
  bf16* att   = v;                       // alias (v dead after k_vt)
  bf16* o1    = (bf16*)(ws + 80 * MB);   // 8MB
  bf16* A2    = (bf16*)(ws + 88 * MB);   // 16MB
  bf16* qr    = A2;                      // alias (A2 dead after conv2 gemm)
  bf16* o2    = (bf16*)(ws + 104 * MB);  // 16MB
  bf16* kr    = o2;                      // alias (o2 dead after rmsnorm)

  auto f2b = [&](const float* in, bf16* out, int n) {
    int n4 = n / 4;
    k_f2b4<<<(n4 + 255) / 256, 256, 0, stream>>>(in, out, n4);
  };

  // 1. v = hs @ Wv.T   (M=4096,N=2048,K=2048; 128^2 tiles -> 512 blocks)
  f2b(Wv, Wslot, 2048 * 2048);
  k_build_a1<<<Tc * Hc / 256, 256, 0, stream>>>(hid, lf1, hsb, A1);
  gemm_pipe<2, 2, 4, 4, true><<<512, 256, 0, stream>>>(hsb, Wslot, v, nullptr, Tc, Pc, Hc);

  // 2. conv1 (as GEMM; M=4096,N=1024,K=4096; 256 blocks)
  f2b(c1w, Wslot, 1024 * 2048 * 2);
  gemm_pipe<2, 2, 4, 4, true><<<256, 256, 0, stream>>>(A1, Wslot, o1, c1b, Tc, 1024, 4096);

  // 3. conv2 (M=4096,N=2048,K=2048; 512 blocks)
  k_build_a2<<<Tc * 1024 / 256, 256, 0, stream>>>(o1, lf2, A2);
  f2b(c2w, Wslot, 2048 * 1024 * 2);
  gemm_pipe<2, 2, 4, 4, true><<<512, 256, 0, stream>>>(A2, Wslot, o2, c2b, Tc, 2048, 2048);

  // 4. residual + rmsnorm
  k_rmsnorm<<<Tc, 256, 0, stream>>>(o2, hid, lng, lfb);

  // 5. qk projection (M=4096,N=4096,K=2048; 256^2 tiles -> 256 blocks, 1/CU)
  f2b(Wqk, Wslot, 4096 * 2048);
  gemm_pipe<2, 4, 8, 4, true><<<256, 512, 0, stream>>>(lfb, Wslot, qkb, nullptr, Tc, 4096, Hc);

  // 6. rope, V transpose, attention (balanced pairs: 8 blocks per (b,h))
  k_rope<<<Tc * NHc, 256, 0, stream>>>(qkb, rot, qr, kr);
  k_vt<<<64 * 32 * 4, 256, 0, stream>>>(v, vT);
  k_attn<<<Bc * NHc * 8, 256, 0, stream>>>(qr, kr, vT, att);

  // 7. output projection (fp32 out; 512 blocks)
  f2b(Wo, Wslot, 2048 * 2048);
  gemm_pipe<2, 2, 4, 4, false><<<512, 256, 0, stream>>>(att, Wslot, outp, nullptr, Tc, 2048, 2048);
}

// Round 7
// 391.346 us; speedup vs baseline: 1.6166x; 1.0270x over previous
//
#include <hip/hip_runtime.h>

typedef __bf16 bf16;
typedef __bf16 bf16x8 __attribute__((ext_vector_type(8)));
typedef __bf16 bf16x4 __attribute__((ext_vector_type(4)));
typedef float f32x4 __attribute__((ext_vector_type(4)));

#define DEVI __device__ __forceinline__

// problem constants
constexpr int Bc = 4, Sc = 1024, Hc = 2048, NHc = 16, HDc = 128;
constexpr int Tc = Bc * Sc;   // 4096
constexpr int Pc = NHc * HDc; // 2048

DEVI void async16(const void* g, void* l) {
  __builtin_amdgcn_global_load_lds(
      (const __attribute__((address_space(1))) unsigned int*)g,
      (__attribute__((address_space(3))) unsigned int*)l, 16, 0, 0);
}

#define BAR() __builtin_amdgcn_s_barrier()
#define LGKM0()                                          \
  do {                                                   \
    asm volatile("s_waitcnt lgkmcnt(0)" ::: "memory");   \
    __builtin_amdgcn_sched_barrier(0);                   \
  } while (0)
#define VM0() asm volatile("s_waitcnt vmcnt(0)" ::: "memory")

// ---------------------------------------------------------------------------
// 8-phase GEMM (m201-style): C[m][n] = sum_k A[m][k]*W[n][k] (+bias)
// BK=64, 2 LDS buffers. Per K-tile: 4 phases, each {ds_read quadrant frags;
// stage t+1 half-tiles (phases 0-1 only -> >=2 phases slack); barrier;
// lgkmcnt(0)+sched_barrier; setprio(1); MH*NH*2 MFMA; setprio(0); barrier}.
// Single vmcnt(0) per K-tile at phase 3 (prefetch long since landed).
// Quadrant order (0,0)(0,1)(1,1)(1,0) shares fragment halves (24 rd/wave/tile).
// Swizzle grp^=row&7 on DMA source and LDS read (rule 21 involution).
// <2,4,8,4> = 256x256; <4,2,4,4> = 256x128. Both 512 thr, 1 block/CU.
// ---------------------------------------------------------------------------
template <int WM, int WN, int MREP, int NREP, bool OUT_BF16>
__global__ __launch_bounds__(512, 2) void gemm8(
    const bf16* __restrict__ A, const bf16* __restrict__ W, void* __restrict__ Cout,
    const float* __restrict__ bias, int M, int N, int K) {
  constexpr int BM = WM * MREP * 16;
  constexpr int BN = WN * NREP * 16;
  constexpr int MH = MREP / 2, NH = NREP / 2;
  constexpr int LA = BM / 128;  // per-thread loads per A half-chunk
  constexpr int LB = BN / 128;
  __shared__ char lds[2][(BM + BN) * 128];

  const int nbx = N / BN;
  const int nwg = (M / BM) * nbx;
  const int wgid = (blockIdx.x & 7) * (nwg >> 3) + (blockIdx.x >> 3);
  const int bx = wgid % nbx, by = wgid / nbx;
  const int m0 = by * BM, n0 = bx * BN;
  const int tid = threadIdx.x;
  const int w = tid >> 6, l = tid & 63;
  const int wm = w / WN, wn = w % WN;
  const int lr = l & 15, hi = l >> 4;

  auto stageA = [&](int buf, int t, int half) {
#pragma unroll
    for (int c = 0; c < LA; ++c) {
      const int ch = c * 512 + tid;
      const int row = half * (BM / 2) + (ch >> 3);
      const int grp = ch & 7;
      async16(A + (size_t)(m0 + row) * K + (t << 6) + ((grp ^ (row & 7)) << 3),
              &lds[buf][row * 128 + grp * 16]);
    }
  };
  auto stageB = [&](int buf, int t, int half) {
#pragma unroll
    for (int c = 0; c < LB; ++c) {
      const int ch = c * 512 + tid;
      const int row = half * (BN / 2) + (ch >> 3);
      const int grp = ch & 7;
      async16(W + (size_t)(n0 + row) * K + (t << 6) + ((grp ^ (row & 7)) << 3),
              &lds[buf][BM * 128 + row * 128 + grp * 16]);
    }
  };
  auto LD = [&](const char* Lp, int row, int g) -> bf16x8 {
    return *(const bf16x8*)(Lp + ((size_t)row << 7) + ((g ^ (row & 7)) << 4));
  };

#define QUAD(MB_, NB_, FB_)                                                     \
  do {                                                                          \
    __builtin_amdgcn_s_setprio(1);                                              \
    _Pragma("unroll") for (int m = 0; m < MH; ++m)                              \
      _Pragma("unroll") for (int n = 0; n < NH; ++n)                            \
        _Pragma("unroll") for (int kk = 0; kk < 2; ++kk)                        \
          acc[(MB_) + m][(NB_) + n] = __builtin_amdgcn_mfma_f32_16x16x32_bf16(  \
              fa[m][kk], FB_[n][kk], acc[(MB_) + m][(NB_) + n], 0, 0, 0);       \
    __builtin_amdgcn_s_setprio(0);                                              \
  } while (0)

  f32x4 acc[MREP][NREP] = {};
  bf16x8 fa[MH][2], fb0[NH][2], fb1[NH][2];
  const int nk = K >> 6;

  stageA(0, 0, 0);
  stageB(0, 0, 0);
  stageB(0, 0, 1);
  stageA(0, 0, 1);
  VM0();
  BAR();

#pragma unroll 1
  for (int t = 0; t < nk; ++t) {
    const char* Lb = lds[t & 1];
    const int nbuf = (t & 1) ^ 1;
    const bool pf = (t + 1 < nk);
    // ---- phase 0: quadrant (0,0); stage A0,B0 of t+1
#pragma unroll
    for (int m = 0; m < MH; ++m) {
      const int r = wm * (MREP * 16) + m * 16 + lr;
      fa[m][0] = LD(Lb, r, hi);
      fa[m][1] = LD(Lb, r, 4 + hi);
    }
#pragma unroll
    for (int n = 0; n < NH; ++n) {
      const int r = BM + wn * (NREP * 16) + n * 16 + lr;
      fb0[n][0] = LD(Lb, r, hi);
      fb0[n][1] = LD(Lb, r, 4 + hi);
    }
    if (pf) {
      stageA(nbuf, t + 1, 0);
      stageB(nbuf, t + 1, 0);
    }
    BAR();
    LGKM0();
    QUAD(0, 0, fb0);
    BAR();
    // ---- phase 1: quadrant (0,1); stage B1,A1 of t+1
#pragma unroll
    for (int n = 0; n < NH; ++n) {
      const int r = BM + wn * (NREP * 16) + (NH + n) * 16 + lr;
      fb1[n][0] = LD(Lb, r, hi);
      fb1[n][1] = LD(Lb, r, 4 + hi);
    }
    if (pf) {
      stageB(nbuf, t + 1, 1);
      stageA(nbuf, t + 1, 1);
    }
    BAR();
    LGKM0();
    QUAD(0, NH, fb1);
    BAR();
    // ---- phase 2: quadrant (1,1); fa <- A half 1 (fa dead since phase 1)
#pragma unroll
    for (int m = 0; m < MH; ++m) {
      const int r = wm * (MREP * 16) + (MH + m) * 16 + lr;
      fa[m][0] = LD(Lb, r, hi);
      fa[m][1] = LD(Lb, r, 4 + hi);
    }
    BAR();
    LGKM0();
    QUAD(MH, NH, fb1);
    BAR();
    // ---- phase 3: quadrant (1,0); certify t+1 staging landed
    QUAD(MH, 0, fb0);
    VM0();  // stages issued >=2 phases ago -> ~no stall; queue empty after
    BAR();
  }
#undef QUAD

#pragma unroll
  for (int ni = 0; ni < NREP; ++ni) {
    const int col = n0 + wn * (NREP * 16) + ni * 16 + lr;
    const float bv = bias ? bias[col] : 0.f;
#pragma unroll
    for (int mi = 0; mi < MREP; ++mi) {
#pragma unroll
      for (int j = 0; j < 4; ++j) {
        const int row = m0 + wm * (MREP * 16) + mi * 16 + (hi << 2) + j;
        const float vv = acc[mi][ni][j] + bv;
        if (OUT_BF16)
          ((bf16*)Cout)[(size_t)row * N + col] = (bf16)vv;
        else
          ((float*)Cout)[(size_t)row * N + col] = vv;
      }
    }
  }
}

// ---------------------------------------------------------------------------
// 2-phase pipelined GEMM (round-6 structure) — kept for conv1 (N=1024).
// ---------------------------------------------------------------------------
template <int WM, int WN, int MREP, int NREP, bool OUT_BF16>
__global__ __launch_bounds__(WM * WN * 64, 2) void gemm_pipe(
    const bf16* __restrict__ A, const bf16* __restrict__ W, void* __restrict__ Cout,
    const float* __restrict__ bias, int M, int N, int K) {
  constexpr int BM = WM * MREP * 16;
  constexpr int BN = WN * NREP * 16;
  constexpr int THREADS = WM * WN * 64;
  constexpr int ROWS = BM + BN;
  constexpr int CHA = BM * 4 / THREADS;
  constexpr int CHB = BN * 4 / THREADS;
  static_assert(CHA + CHB == 4, "vmcnt ledger assumes 4 loads/thread/stage");
  __shared__ bf16 lds[4][ROWS * 32];

  const int nbx = N / BN;
  const int nwg = (M / BM) * nbx;
  const int wgid = (blockIdx.x & 7) * (nwg >> 3) + (blockIdx.x >> 3);
  const int bx = wgid % nbx, by = wgid / nbx;
  const int m0 = by * BM, n0 = bx * BN;
  const int tid = threadIdx.x;
  const int w = tid >> 6, l = tid & 63;
  const int wm = w / WN, wn = w % WN;
  const int lr = l & 15;
  const int hi = l >> 4;

  auto stage = [&](int slot, int t) {
    const int k0 = t << 5;
#pragma unroll
    for (int c = 0; c < CHA; ++c) {
      const int ch = c * THREADS + tid;
      const int row = ch >> 2, cg = ch & 3;
      const int gc = (cg ^ ((row >> 1) & 3)) << 3;
      async16(A + (size_t)(m0 + row) * K + k0 + gc, (char*)&lds[slot][0] + ch * 16);
    }
#pragma unroll
    for (int c = 0; c < CHB; ++c) {
      const int ch = c * THREADS + tid;
      const int row = ch >> 2, cg = ch & 3;
      const int gc = (cg ^ ((row >> 1) & 3)) << 3;
      async16(W + (size_t)(n0 + row) * K + k0 + gc,
              (char*)&lds[slot][0] + (BM * 4 + ch) * 16);
    }
  };

  f32x4 acc[MREP][NREP] = {};
  const int nk = K >> 5;

  stage(0, 0);
  stage(1, 1);
  stage(2, 2);
  asm volatile("s_waitcnt vmcnt(8)" ::: "memory");
  __builtin_amdgcn_s_barrier();
  __builtin_amdgcn_sched_barrier(0);

  bf16x8 fAc[MREP], fBc[NREP], fAn[MREP], fBn[NREP];
  {
    const char* nb = (const char*)&lds[0][0];
#pragma unroll
    for (int mi = 0; mi < MREP; ++mi) {
      const int r = wm * (MREP * 16) + mi * 16 + lr;
      fAc[mi] = *(const bf16x8*)(nb + r * 64 + ((hi ^ ((r >> 1) & 3)) << 4));
    }
#pragma unroll
    for (int ni = 0; ni < NREP; ++ni) {
      const int r = BM + wn * (NREP * 16) + ni * 16 + lr;
      fBc[ni] = *(const bf16x8*)(nb + r * 64 + ((hi ^ ((r >> 1) & 3)) << 4));
    }
  }

#define GSTEP(T_, CA, CB, NA, NB)                                              \
  do {                                                                         \
    if ((T_) + 2 < nk) asm volatile("s_waitcnt vmcnt(4)" ::: "memory");        \
    else               asm volatile("s_waitcnt vmcnt(0)" ::: "memory");        \
    __builtin_amdgcn_s_barrier();                                              \
    __builtin_amdgcn_sched_barrier(0);                                         \
    if ((T_) + 3 < nk) stage(((T_) + 3) & 3, (T_) + 3);                        \
    if ((T_) + 1 < nk) {                                                       \
      const char* nb = (const char*)&lds[((T_) + 1) & 3][0];                   \
      _Pragma("unroll") for (int mi = 0; mi < MREP; ++mi) {                    \
        const int r = wm * (MREP * 16) + mi * 16 + lr;                         \
        NA[mi] = *(const bf16x8*)(nb + r * 64 + ((hi ^ ((r >> 1) & 3)) << 4)); \
      }                                                                        \
      _Pragma("unroll") for (int ni = 0; ni < NREP; ++ni) {                    \
        const int r = BM + wn * (NREP * 16) + ni * 16 + lr;                    \
        NB[ni] = *(const bf16x8*)(nb + r * 64 + ((hi ^ ((r >> 1) & 3)) << 4)); \
      }                                                                        \
    }                                                                          \
    __builtin_amdgcn_s_setprio(1);                                             \
    _Pragma("unroll") for (int mi = 0; mi < MREP; ++mi)                        \
      _Pragma("unroll") for (int ni = 0; ni < NREP; ++ni)                      \
        acc[mi][ni] =                                                          \
            __builtin_amdgcn_mfma_f32_16x16x32_bf16(CA[mi], CB[ni], acc[mi][ni], 0, 0, 0); \
    __builtin_amdgcn_s_setprio(0);                                             \
  } while (0)

  for (int t = 0; t < nk; t += 2) {
    GSTEP(t, fAc, fBc, fAn, fBn);
    GSTEP(t + 1, fAn, fBn, fAc, fBc);
  }
#undef GSTEP

#pragma unroll
  for (int ni = 0; ni < NREP; ++ni) {
    const int col = n0 + wn * (NREP * 16) + ni * 16 + lr;
    const float bv = bias ? bias[col] : 0.f;
#pragma unroll
    for (int mi = 0; mi < MREP; ++mi) {
#pragma unroll
      for (int j = 0; j < 4; ++j) {
        const int row = m0 + wm * (MREP * 16) + mi * 16 + (hi << 2) + j;
        const float vv = acc[mi][ni][j] + bv;
        if (OUT_BF16)
          ((bf16*)Cout)[(size_t)row * N + col] = (bf16)vv;
        else
          ((float*)Cout)[(size_t)row * N + col] = vv;
      }
    }
  }
}

// ---------------------------------------------------------------------------
// fp32 -> bf16 weight conversion (vectorized by 4)
// ---------------------------------------------------------------------------
__global__ void k_f2b4(const float* __restrict__ in, bf16* __restrict__ out, int n4) {
  int i = blockIdx.x * 256 + threadIdx.x;
  if (i >= n4) return;
  float4 v = ((const float4*)in)[i];
  bf16x4 o = {(bf16)v.x, (bf16)v.y, (bf16)v.z, (bf16)v.w};
  ((bf16x4*)out)[i] = o;
}

// hidden fp32 -> hsb bf16, and conv1 interleaved input A1[t][2h+tap]
__global__ void k_build_a1(const float* __restrict__ hid, const float* __restrict__ lf1,
                           bf16* __restrict__ hsb, bf16* __restrict__ A1) {
  int idx = blockIdx.x * 256 + threadIdx.x;  // < T*H
  int t = idx >> 11, h = idx & 2047;
  float x = hid[idx];
  hsb[idx] = (bf16)x;
  float xp;
  if ((t & (Sc - 1)) == 0)
    xp = lf1[(t >> 10) * Hc + h];
  else
    xp = hid[idx - Hc];
  size_t a = ((size_t)t << 12) + 2 * h;
  A1[a] = (bf16)xp;
  A1[a + 1] = (bf16)x;
}

// conv2 interleaved input A2[t][2c+tap] from o1
__global__ void k_build_a2(const bf16* __restrict__ o1, const float* __restrict__ lf2,
                           bf16* __restrict__ A2) {
  int idx = blockIdx.x * 256 + threadIdx.x;  // < T*1024
  int t = idx >> 10, c = idx & 1023;
  bf16 cur = o1[idx];
  bf16 prev;
  if ((t & (Sc - 1)) == 0)
    prev = (bf16)lf2[(t >> 10) * 1024 + c];
  else
    prev = o1[idx - 1024];
  size_t a = ((size_t)t << 11) + 2 * c;
  A2[a] = prev;
  A2[a + 1] = cur;
}

// lf = rmsnorm(o2 + hid) * g   (one block per row, 256 thr x 8 elems)
__global__ __launch_bounds__(256) void k_rmsnorm(const bf16* __restrict__ o2,
                                                 const float* __restrict__ hid,
                                                 const float* __restrict__ g,
                                                 bf16* __restrict__ lf) {
  int t = blockIdx.x, tid = threadIdx.x;
  size_t base = ((size_t)t << 11) + tid * 8;
  bf16x8 ov = *(const bf16x8*)&o2[base];
  const float* hp = &hid[base];
  float vals[8];
  float ss = 0.f;
#pragma unroll
  for (int i = 0; i < 8; ++i) {
    float x = (float)ov[i] + hp[i];
    vals[i] = x;
    ss += x * x;
  }
#pragma unroll
  for (int off = 1; off < 64; off <<= 1) ss += __shfl_xor(ss, off);
  __shared__ float red[4];
  if ((tid & 63) == 0) red[tid >> 6] = ss;
  __syncthreads();
  float tot = red[0] + red[1] + red[2] + red[3];
  float inv = rsqrtf(tot * (1.f / 2048.f) + 1e-6f);
  bf16x8 o;
#pragma unroll
  for (int i = 0; i < 8; ++i) o[i] = (bf16)(vals[i] * inv * g[tid * 8 + i]);
  *(bf16x8*)&lf[base] = o;
}

// RoPE on qk (T,NH,256) -> qr,kr laid out (B,NH,S,HD) bf16
__global__ void k_rope(const bf16* __restrict__ qk, const float* __restrict__ rot,
                       bf16* __restrict__ qr, bf16* __restrict__ kr) {
  int bid = blockIdx.x;  // T*NH
  int n = bid & 15, t = bid >> 4;
  int s = t & (Sc - 1), b = t >> 10;
  int tid = threadIdx.x;
  int isk = tid >> 7, d = tid & 127;
  const bf16* src = qk + ((size_t)t << 12) + n * 256 + isk * 128;
  float val = (float)src[d];
  float outv = val;
  if (d < 64) {
    float f = rot[s * 64 + d];
    float c = cosf(f), sn = sinf(f);
    float other = (float)src[d ^ 32];
    outv = (d < 32) ? (val * c - other * sn) : (val * c + other * sn);
  }
  bf16* dst = isk ? kr : qr;
  dst[((size_t)((b * 16 + n) * 1024 + s) << 7) + d] = (bf16)outv;
}

// v (T,P) -> vT (B,NH,HD,S), 32x32 LDS tile transpose
__global__ void k_vt(const bf16* __restrict__ v, bf16* __restrict__ vT) {
  __shared__ bf16 tile[32][33];
  int bid = blockIdx.x;
  int dt = bid & 3;          // HD/32
  int st = (bid >> 2) & 31;  // S/32
  int bn = bid >> 7;         // b*NH+n
  int b = bn >> 4, n = bn & 15;
  int tx = threadIdx.x & 31, ty = threadIdx.x >> 5;  // 32 x 8
#pragma unroll
  for (int i = 0; i < 4; ++i) {
    int s = st * 32 + ty + i * 8;
    int d = dt * 32 + tx;
    tile[ty + i * 8][tx] = v[(size_t)(b * 1024 + s) * 2048 + n * 128 + d];
  }
  __syncthreads();
#pragma unroll
  for (int i = 0; i < 4; ++i) {
    int d = dt * 32 + ty + i * 8;
    int s = st * 32 + tx;
    vT[((size_t)(bn * 128 + d)) * 1024 + s] = tile[tx][ty + i * 8];
  }
}

// ---------------------------------------------------------------------------
// causal flash attention v2: LDS-staged K/V, double-buffered global_load_lds,
// balanced q-tile pairs (pr, 15-pr), XCD-local (b,h) mapping.
// ---------------------------------------------------------------------------
__global__ __launch_bounds__(256, 2) void k_attn(const bf16* __restrict__ qr,
                                                 const bf16* __restrict__ kr,
                                                 const bf16* __restrict__ vT,
                                                 bf16* __restrict__ att) {
  __shared__ bf16 Ks[2][64 * 128];
  __shared__ bf16 Vs[2][128 * 64];
  __shared__ bf16 plds[4][16 * 64];
  const int bid = blockIdx.x;
  const int xcd = bid & 7, jj = bid >> 3;
  const int bn = xcd * 8 + (jj >> 3);
  const int pr = jj & 7;
  const int tid = threadIdx.x, w = tid >> 6, l = tid & 63;
  const int lr = l & 15, hi = l >> 4;
  const bf16* kb = kr + ((size_t)bn << 17);
  const bf16* vb = vT + ((size_t)bn << 17);
  const int b = bn >> 4, hh = bn & 15;
  const float scaling = 0.08838834764831845f;

  auto stage = [&](int buf, int kt) {
#pragma unroll
    for (int c = 0; c < 4; ++c) {
      int chunk = c * 256 + tid;
      int prow = chunk >> 4, pcg = chunk & 15;
      async16(kb + ((size_t)(kt * 64 + prow) << 7) + ((pcg ^ (prow & 7)) << 3),
              (char*)&Ks[buf][0] + chunk * 16);
    }
#pragma unroll
    for (int c = 0; c < 4; ++c) {
      int chunk = c * 256 + tid;
      int prow = chunk >> 3, pcg = chunk & 7;
      async16(vb + ((size_t)prow << 10) + kt * 64 + ((pcg ^ (prow & 7)) << 3),
              (char*)&Vs[buf][0] + chunk * 16);
    }
  };

#pragma unroll 1
  for (int phase = 0; phase < 2; ++phase) {
    const int qt = phase ? (15 - pr) : pr;
    const int qg0 = qt * 64 + w * 16;
    const bf16* qb = qr + ((size_t)(bn * 1024 + qg0) << 7);
    bf16x8 qf[4];
#pragma unroll
    for (int ks = 0; ks < 4; ++ks) qf[ks] = *(const bf16x8*)&qb[lr * 128 + ks * 32 + hi * 8];
    f32x4 oacc[8] = {};
    float mrow[4] = {-1e30f, -1e30f, -1e30f, -1e30f};
    float lrow[4] = {0.f, 0.f, 0.f, 0.f};
    const int nkb = qt + 1;

    stage(0, 0);
    __syncthreads();

    for (int kbt = 0; kbt < nkb; ++kbt) {
      const int cur = kbt & 1;
      if (kbt + 1 < nkb) stage(cur ^ 1, kbt + 1);

      f32x4 sacc[4] = {};
#pragma unroll
      for (int n = 0; n < 4; ++n) {
        const int krow = n * 16 + lr;
#pragma unroll
        for (int ks = 0; ks < 4; ++ks) {
          bf16x8 kf = *(const bf16x8*)&Ks[cur][(krow << 7) + ((((ks << 2) | hi) ^ (krow & 7)) << 3)];
          sacc[n] = __builtin_amdgcn_mfma_f32_16x16x32_bf16(qf[ks], kf, sacc[n], 0, 0, 0);
        }
      }
      const bool needmask = (kbt * 64 + 63 > qg0);
#pragma unroll
      for (int n = 0; n < 4; ++n) {
        int kg = kbt * 64 + n * 16 + lr;
#pragma unroll
        for (int j = 0; j < 4; ++j) {
          float sv = sacc[n][j] * scaling;
          if (needmask && kg > qg0 + hi * 4 + j) sv = -1e30f;
          sacc[n][j] = sv;
        }
      }
      float sf[4];
#pragma unroll
      for (int j = 0; j < 4; ++j) {
        float pm = fmaxf(fmaxf(sacc[0][j], sacc[1][j]), fmaxf(sacc[2][j], sacc[3][j]));
        pm = fmaxf(pm, __shfl_xor(pm, 1));
        pm = fmaxf(pm, __shfl_xor(pm, 2));
        pm = fmaxf(pm, __shfl_xor(pm, 4));
        pm = fmaxf(pm, __shfl_xor(pm, 8));
        float mn = fmaxf(mrow[j], pm);
        sf[j] = __expf(mrow[j] - mn);
        mrow[j] = mn;
      }
#pragma unroll
      for (int n = 0; n < 4; ++n)
#pragma unroll
        for (int j = 0; j < 4; ++j) sacc[n][j] = __expf(sacc[n][j] - mrow[j]);
#pragma unroll
      for (int j = 0; j < 4; ++j) {
        float ps = sacc[0][j] + sacc[1][j] + sacc[2][j] + sacc[3][j];
        ps += __shfl_xor(ps, 1);
        ps += __shfl_xor(ps, 2);
        ps += __shfl_xor(ps, 4);
        ps += __shfl_xor(ps, 8);
        lrow[j] = lrow[j] * sf[j] + ps;
      }
#pragma unroll
      for (int dt = 0; dt < 8; ++dt)
#pragma unroll
        for (int j = 0; j < 4; ++j) oacc[dt][j] *= sf[j];
#pragma unroll
      for (int n = 0; n < 4; ++n)
#pragma unroll
        for (int j = 0; j < 4; ++j)
          plds[w][(hi * 4 + j) * 64 + n * 16 + lr] = (bf16)sacc[n][j];
      asm volatile("s_waitcnt lgkmcnt(0)" ::: "memory");
#pragma unroll
      for (int ks2 = 0; ks2 < 2; ++ks2) {
        bf16x8 pf = *(const bf16x8*)&plds[w][lr * 64 + ks2 * 32 + hi * 8];
#pragma unroll
        for (int dt = 0; dt < 8; ++dt) {
          const int vrow = dt * 16 + lr;
          bf16x8 vf = *(const bf16x8*)&Vs[cur][(vrow << 6) + ((((ks2 << 2) | hi) ^ (lr & 7)) << 3)];
          oacc[dt] = __builtin_amdgcn_mfma_f32_16x16x32_bf16(pf, vf, oacc[dt], 0, 0, 0);
        }
      }
      __syncthreads();
    }

#pragma unroll
    for (int j = 0; j < 4; ++j) {
      float inv = 1.f / lrow[j];
      int qg = qg0 + hi * 4 + j;
      size_t obase = ((size_t)(b * 1024 + qg) << 11) + hh * 128;
#pragma unroll
      for (int dt = 0; dt < 8; ++dt) att[obase + dt * 16 + lr] = (bf16)(oacc[dt][j] * inv);
    }
  }
}

// ---------------------------------------------------------------------------
// Workspace plan (120 MB total, sequential liveness — one stream, in-order):
//   W    0-16    weight slot (reused: Wv, c1w, c2w, Wqk(16MB), Wo)
//   S0  16-48    A1 (32MB)            -> qkb (32MB)
//   S1  48-64    hsb                  -> lfb      -> vT
//   S2  64-80    v                    -> att
//   S3  80-88    o1
//   S4  88-104   A2                   -> qr
//   S5 104-120   o2                   -> kr
// ---------------------------------------------------------------------------
extern "C" void kernel_launch(void* const* d_in, const int* in_sizes, int n_in,
                              void* d_out, int out_size, void* d_ws, size_t ws_size,
                              hipStream_t stream) {
  const float* hid = (const float*)d_in[1];
  const float* rot = (const float*)d_in[2];
  const float* lf1 = (const float*)d_in[3];
  const float* lf2 = (const float*)d_in[4];
  const float* Wqk = (const float*)d_in[5];
  const float* Wv  = (const float*)d_in[6];
  const float* Wo  = (const float*)d_in[7];
  const float* c1w = (const float*)d_in[8];
  const float* c1b = (const float*)d_in[9];
  const float* c2w = (const float*)d_in[10];
  const float* c2b = (const float*)d_in[11];
  const float* lng = (const float*)d_in[12];
  float* outp = (float*)d_out;
  char* ws = (char*)d_ws;

  const size_t MB = 1ull << 20;
  bf16* Wslot = (bf16*)(ws + 0 * MB);
  bf16* A1    = (bf16*)(ws + 16 * MB);
  bf16* qkb   = A1;
  bf16* hsb   = (bf16*)(ws + 48 * MB);
  bf16* lfb   = hsb;
  bf16* vT    = hsb;
  bf16* v     = (bf16*)(ws + 64 * MB);
  bf16* att   = v;
  bf16* o1    = (bf16*)(ws + 80 * MB);
  bf16* A2    = (bf16*)(ws + 88 * MB);
  bf16* qr    = A2;
  bf16* o2    = (bf16*)(ws + 104 * MB);
  bf16* kr    = o2;

  auto f2b = [&](const float* in, bf16* out, int n) {
    int n4 = n / 4;
    k_f2b4<<<(n4 + 255) / 256, 256, 0, stream>>>(in, out, n4);
  };

  // 1. v = hs @ Wv.T   (M=4096,N=2048,K=2048; 256x128 8-phase -> 256 blocks)
  f2b(Wv, Wslot, 2048 * 2048);
  k_build_a1<<<Tc * Hc / 256, 256, 0, stream>>>(hid, lf1, hsb, A1);
  gemm8<4, 2, 4, 4, true><<<256, 512, 0, stream>>>(hsb, Wslot, v, nullptr, Tc, Pc, Hc);

  // 2. conv1 (as GEMM; M=4096,N=1024,K=4096; 128^2 2-phase, 256 blocks)
  f2b(c1w, Wslot, 1024 * 2048 * 2);
  gemm_pipe<2, 2, 4, 4, true><<<256, 256, 0, stream>>>(A1, Wslot, o1, c1b, Tc, 1024, 4096);

  // 3. conv2 (M=4096,N=2048,K=2048; 256x128 8-phase)
  k_build_a2<<<Tc * 1024 / 256, 256, 0, stream>>>(o1, lf2, A2);
  f2b(c2w, Wslot, 2048 * 1024 * 2);
  gemm8<4, 2, 4, 4, true><<<256, 512, 0, stream>>>(A2, Wslot, o2, c2b, Tc, 2048, 2048);

  // 4. residual + rmsnorm
  k_rmsnorm<<<Tc, 256, 0, stream>>>(o2, hid, lng, lfb);

  // 5. qk projection (M=4096,N=4096,K=2048; 256^2 8-phase -> 256 blocks)
  f2b(Wqk, Wslot, 4096 * 2048);
  gemm8<2, 4, 8, 4, true><<<256, 512, 0, stream>>>(lfb, Wslot, qkb, nullptr, Tc, 4096, Hc);

  // 6. rope, V transpose, attention
  k_rope<<<Tc * NHc, 256, 0, stream>>>(qkb, rot, qr, kr);
  k_vt<<<64 * 32 * 4, 256, 0, stream>>>(v, vT);
  k_attn<<<Bc * NHc * 8, 256, 0, stream>>>(qr, kr, vT, att);

  // 7. output projection (fp32 out; 256x128 8-phase)
  f2b(Wo, Wslot, 2048 * 2048);
  gemm8<4, 2, 4, 4, false><<<256, 512, 0, stream>>>(att, Wslot, outp, nullptr, Tc, 2048, 2048);
}

// Round 8
// 389.857 us; speedup vs baseline: 1.6228x; 1.0038x over previous
//
#include <hip/hip_runtime.h>

typedef __bf16 bf16;
typedef __bf16 bf16x8 __attribute__((ext_vector_type(8)));
typedef __bf16 bf16x4 __attribute__((ext_vector_type(4)));
typedef float f32x4 __attribute__((ext_vector_type(4)));

#define DEVI __device__ __forceinline__

// problem constants
constexpr int Bc = 4, Sc = 1024, Hc = 2048, NHc = 16, HDc = 128;
constexpr int Tc = Bc * Sc;   // 4096
constexpr int Pc = NHc * HDc; // 2048

DEVI void async16(const void* g, void* l) {
  __builtin_amdgcn_global_load_lds(
      (const __attribute__((address_space(1))) unsigned int*)g,
      (__attribute__((address_space(3))) unsigned int*)l, 16, 0, 0);
}

#define BAR() __builtin_amdgcn_s_barrier()
#define LGKM0()                                          \
  do {                                                   \
    asm volatile("s_waitcnt lgkmcnt(0)" ::: "memory");   \
    __builtin_amdgcn_sched_barrier(0);                   \
  } while (0)
#define VM0() asm volatile("s_waitcnt vmcnt(0)" ::: "memory")

// ---------------------------------------------------------------------------
// 8-phase GEMM (m201-style) + LDS-staged coalesced epilogue.
// K-loop identical to round 7. Epilogue: acc -> LDS (bf16/f32, XOR-swizzled
// 16B groups g^=row&7: 2-way max write conflict = free) -> barrier ->
// contiguous bf16x8/f32x4 stores (consecutive lanes = consecutive 16B =
// full-line HBM writes; kills the 2.3x write amplification seen in R5-R7).
// ---------------------------------------------------------------------------
template <int WM, int WN, int MREP, int NREP, bool OUT_BF16>
__global__ __launch_bounds__(512, 2) void gemm8(
    const bf16* __restrict__ A, const bf16* __restrict__ W, void* __restrict__ Cout,
    const float* __restrict__ bias, int M, int N, int K) {
  constexpr int BM = WM * MREP * 16;
  constexpr int BN = WN * NREP * 16;
  constexpr int MH = MREP / 2, NH = NREP / 2;
  constexpr int LA = BM / 128;
  constexpr int LB = BN / 128;
  constexpr int STG = (BM + BN) * 128;            // one staging buffer, bytes
  constexpr int OUTB = OUT_BF16 ? 2 : 4;
  constexpr int CBYTES = BM * BN * OUTB;
  constexpr int LDSB = (2 * STG > CBYTES) ? 2 * STG : CBYTES;
  __shared__ char lds[LDSB];

  const int nbx = N / BN;
  const int nwg = (M / BM) * nbx;
  const int wgid = (blockIdx.x & 7) * (nwg >> 3) + (blockIdx.x >> 3);
  const int bx = wgid % nbx, by = wgid / nbx;
  const int m0 = by * BM, n0 = bx * BN;
  const int tid = threadIdx.x;
  const int w = tid >> 6, l = tid & 63;
  const int wm = w / WN, wn = w % WN;
  const int lr = l & 15, hi = l >> 4;

  auto stageA = [&](int buf, int t, int half) {
#pragma unroll
    for (int c = 0; c < LA; ++c) {
      const int ch = c * 512 + tid;
      const int row = half * (BM / 2) + (ch >> 3);
      const int grp = ch & 7;
      async16(A + (size_t)(m0 + row) * K + (t << 6) + ((grp ^ (row & 7)) << 3),
              &lds[buf * STG + row * 128 + grp * 16]);
    }
  };
  auto stageB = [&](int buf, int t, int half) {
#pragma unroll
    for (int c = 0; c < LB; ++c) {
      const int ch = c * 512 + tid;
      const int row = half * (BN / 2) + (ch >> 3);
      const int grp = ch & 7;
      async16(W + (size_t)(n0 + row) * K + (t << 6) + ((grp ^ (row & 7)) << 3),
              &lds[buf * STG + BM * 128 + row * 128 + grp * 16]);
    }
  };
  auto LD = [&](const char* Lp, int row, int g) -> bf16x8 {
    return *(const bf16x8*)(Lp + ((size_t)row << 7) + ((g ^ (row & 7)) << 4));
  };

#define QUAD(MB_, NB_, FB_)                                                     \
  do {                                                                          \
    __builtin_amdgcn_s_setprio(1);                                              \
    _Pragma("unroll") for (int m = 0; m < MH; ++m)                              \
      _Pragma("unroll") for (int n = 0; n < NH; ++n)                            \
        _Pragma("unroll") for (int kk = 0; kk < 2; ++kk)                        \
          acc[(MB_) + m][(NB_) + n] = __builtin_amdgcn_mfma_f32_16x16x32_bf16(  \
              fa[m][kk], FB_[n][kk], acc[(MB_) + m][(NB_) + n], 0, 0, 0);       \
    __builtin_amdgcn_s_setprio(0);                                              \
  } while (0)

  f32x4 acc[MREP][NREP] = {};
  bf16x8 fa[MH][2], fb0[NH][2], fb1[NH][2];
  const int nk = K >> 6;

  stageA(0, 0, 0);
  stageB(0, 0, 0);
  stageB(0, 0, 1);
  stageA(0, 0, 1);
  VM0();
  BAR();

#pragma unroll 1
  for (int t = 0; t < nk; ++t) {
    const char* Lb = &lds[(t & 1) * STG];
    const int nbuf = (t & 1) ^ 1;
    const bool pf = (t + 1 < nk);
    // ---- phase 0: quadrant (0,0); stage A0,B0 of t+1
#pragma unroll
    for (int m = 0; m < MH; ++m) {
      const int r = wm * (MREP * 16) + m * 16 + lr;
      fa[m][0] = LD(Lb, r, hi);
      fa[m][1] = LD(Lb, r, 4 + hi);
    }
#pragma unroll
    for (int n = 0; n < NH; ++n) {
      const int r = BM + wn * (NREP * 16) + n * 16 + lr;
      fb0[n][0] = LD(Lb, r, hi);
      fb0[n][1] = LD(Lb, r, 4 + hi);
    }
    if (pf) {
      stageA(nbuf, t + 1, 0);
      stageB(nbuf, t + 1, 0);
    }
    BAR();
    LGKM0();
    QUAD(0, 0, fb0);
    BAR();
    // ---- phase 1: quadrant (0,1); stage B1,A1 of t+1
#pragma unroll
    for (int n = 0; n < NH; ++n) {
      const int r = BM + wn * (NREP * 16) + (NH + n) * 16 + lr;
      fb1[n][0] = LD(Lb, r, hi);
      fb1[n][1] = LD(Lb, r, 4 + hi);
    }
    if (pf) {
      stageB(nbuf, t + 1, 1);
      stageA(nbuf, t + 1, 1);
    }
    BAR();
    LGKM0();
    QUAD(0, NH, fb1);
    BAR();
    // ---- phase 2: quadrant (1,1); fa <- A half 1
#pragma unroll
    for (int m = 0; m < MH; ++m) {
      const int r = wm * (MREP * 16) + (MH + m) * 16 + lr;
      fa[m][0] = LD(Lb, r, hi);
      fa[m][1] = LD(Lb, r, 4 + hi);
    }
    BAR();
    LGKM0();
    QUAD(MH, NH, fb1);
    BAR();
    // ---- phase 3: quadrant (1,0); certify t+1 staging landed
    QUAD(MH, 0, fb0);
    VM0();
    BAR();
  }
#undef QUAD

  // ---- LDS-staged coalesced epilogue ----
  if constexpr (OUT_BF16) {
    bf16* cl = (bf16*)lds;
#pragma unroll
    for (int mi = 0; mi < MREP; ++mi) {
#pragma unroll
      for (int ni = 0; ni < NREP; ++ni) {
        const int col = wn * (NREP * 16) + ni * 16 + lr;
        const float bv = bias ? bias[n0 + col] : 0.f;
#pragma unroll
        for (int j = 0; j < 4; ++j) {
          const int row = wm * (MREP * 16) + mi * 16 + (hi << 2) + j;
          cl[row * BN + ((((col >> 3) ^ (row & 7)) << 3) | (col & 7))] =
              (bf16)(acc[mi][ni][j] + bv);
        }
      }
    }
    __syncthreads();
    constexpr int GPR = BN / 8;            // 16B groups per row
    constexpr int PT = BM * GPR / 512;
#pragma unroll
    for (int c = 0; c < PT; ++c) {
      const int ch = c * 512 + tid;
      const int row = ch / GPR, g = ch % GPR;
      bf16x8 vv = *(const bf16x8*)&cl[row * BN + ((g ^ (row & 7)) << 3)];
      *(bf16x8*)&((bf16*)Cout)[(size_t)(m0 + row) * N + n0 + g * 8] = vv;
    }
  } else {
    float* cl = (float*)lds;
#pragma unroll
    for (int mi = 0; mi < MREP; ++mi) {
#pragma unroll
      for (int ni = 0; ni < NREP; ++ni) {
        const int col = wn * (NREP * 16) + ni * 16 + lr;
        const float bv = bias ? bias[n0 + col] : 0.f;
#pragma unroll
        for (int j = 0; j < 4; ++j) {
          const int row = wm * (MREP * 16) + mi * 16 + (hi << 2) + j;
          cl[row * BN + ((((col >> 2) ^ (row & 7)) << 2) | (col & 3))] =
              acc[mi][ni][j] + bv;
        }
      }
    }
    __syncthreads();
    constexpr int GPR = BN / 4;            // 16B groups per row
    constexpr int PT = BM * GPR / 512;
#pragma unroll
    for (int c = 0; c < PT; ++c) {
      const int ch = c * 512 + tid;
      const int row = ch / GPR, g = ch % GPR;
      f32x4 vv = *(const f32x4*)&cl[row * BN + ((g ^ (row & 7)) << 2)];
      *(f32x4*)&((float*)Cout)[(size_t)(m0 + row) * N + n0 + g * 4] = vv;
    }
  }
}

// ---------------------------------------------------------------------------
// 2-phase pipelined GEMM (round-6 structure) + LDS-staged epilogue — conv1.
// ---------------------------------------------------------------------------
template <int WM, int WN, int MREP, int NREP, bool OUT_BF16>
__global__ __launch_bounds__(WM * WN * 64, 2) void gemm_pipe(
    const bf16* __restrict__ A, const bf16* __restrict__ W, void* __restrict__ Cout,
    const float* __restrict__ bias, int M, int N, int K) {
  constexpr int BM = WM * MREP * 16;
  constexpr int BN = WN * NREP * 16;
  constexpr int THREADS = WM * WN * 64;
  constexpr int ROWS = BM + BN;
  constexpr int CHA = BM * 4 / THREADS;
  constexpr int CHB = BN * 4 / THREADS;
  static_assert(CHA + CHB == 4, "vmcnt ledger assumes 4 loads/thread/stage");
  __shared__ bf16 lds[4][ROWS * 32];
  static_assert(BM * BN * 2 <= sizeof(lds), "C tile must fit LDS for epilogue");

  const int nbx = N / BN;
  const int nwg = (M / BM) * nbx;
  const int wgid = (blockIdx.x & 7) * (nwg >> 3) + (blockIdx.x >> 3);
  const int bx = wgid % nbx, by = wgid / nbx;
  const int m0 = by * BM, n0 = bx * BN;
  const int tid = threadIdx.x;
  const int w = tid >> 6, l = tid & 63;
  const int wm = w / WN, wn = w % WN;
  const int lr = l & 15;
  const int hi = l >> 4;

  auto stage = [&](int slot, int t) {
    const int k0 = t << 5;
#pragma unroll
    for (int c = 0; c < CHA; ++c) {
      const int ch = c * THREADS + tid;
      const int row = ch >> 2, cg = ch & 3;
      const int gc = (cg ^ ((row >> 1) & 3)) << 3;
      async16(A + (size_t)(m0 + row) * K + k0 + gc, (char*)&lds[slot][0] + ch * 16);
    }
#pragma unroll
    for (int c = 0; c < CHB; ++c) {
      const int ch = c * THREADS + tid;
      const int row = ch >> 2, cg = ch & 3;
      const int gc = (cg ^ ((row >> 1) & 3)) << 3;
      async16(W + (size_t)(n0 + row) * K + k0 + gc,
              (char*)&lds[slot][0] + (BM * 4 + ch) * 16);
    }
  };

  f32x4 acc[MREP][NREP] = {};
  const int nk = K >> 5;

  stage(0, 0);
  stage(1, 1);
  stage(2, 2);
  asm volatile("s_waitcnt vmcnt(8)" ::: "memory");
  __builtin_amdgcn_s_barrier();
  __builtin_amdgcn_sched_barrier(0);

  bf16x8 fAc[MREP], fBc[NREP], fAn[MREP], fBn[NREP];
  {
    const char* nb = (const char*)&lds[0][0];
#pragma unroll
    for (int mi = 0; mi < MREP; ++mi) {
      const int r = wm * (MREP * 16) + mi * 16 + lr;
      fAc[mi] = *(const bf16x8*)(nb + r * 64 + ((hi ^ ((r >> 1) & 3)) << 4));
    }
#pragma unroll
    for (int ni = 0; ni < NREP; ++ni) {
      const int r = BM + wn * (NREP * 16) + ni * 16 + lr;
      fBc[ni] = *(const bf16x8*)(nb + r * 64 + ((hi ^ ((r >> 1) & 3)) << 4));
    }
  }

#define GSTEP(T_, CA, CB, NA, NB)                                              \
  do {                                                                         \
    if ((T_) + 2 < nk) asm volatile("s_waitcnt vmcnt(4)" ::: "memory");        \
    else               asm volatile("s_waitcnt vmcnt(0)" ::: "memory");        \
    __builtin_amdgcn_s_barrier();                                              \
    __builtin_amdgcn_sched_barrier(0);                                         \
    if ((T_) + 3 < nk) stage(((T_) + 3) & 3, (T_) + 3);                        \
    if ((T_) + 1 < nk) {                                                       \
      const char* nb = (const char*)&lds[((T_) + 1) & 3][0];                   \
      _Pragma("unroll") for (int mi = 0; mi < MREP; ++mi) {                    \
        const int r = wm * (MREP * 16) + mi * 16 + lr;                         \
        NA[mi] = *(const bf16x8*)(nb + r * 64 + ((hi ^ ((r >> 1) & 3)) << 4)); \
      }                                                                        \
      _Pragma("unroll") for (int ni = 0; ni < NREP; ++ni) {                    \
        const int r = BM + wn * (NREP * 16) + ni * 16 + lr;                    \
        NB[ni] = *(const bf16x8*)(nb + r * 64 + ((hi ^ ((r >> 1) & 3)) << 4)); \
      }                                                                        \
    }                                                                          \
    __builtin_amdgcn_s_setprio(1);                                             \
    _Pragma("unroll") for (int mi = 0; mi < MREP; ++mi)                        \
      _Pragma("unroll") for (int ni = 0; ni < NREP; ++ni)                      \
        acc[mi][ni] =                                                          \
            __builtin_amdgcn_mfma_f32_16x16x32_bf16(CA[mi], CB[ni], acc[mi][ni], 0, 0, 0); \
    __builtin_amdgcn_s_setprio(0);                                             \
  } while (0)

  for (int t = 0; t < nk; t += 2) {
    GSTEP(t, fAc, fBc, fAn, fBn);
    GSTEP(t + 1, fAn, fBn, fAc, fBc);
  }
#undef GSTEP

  // ---- LDS-staged coalesced epilogue (bf16) ----
  __syncthreads();
  {
    bf16* cl = (bf16*)&lds[0][0];
#pragma unroll
    for (int mi = 0; mi < MREP; ++mi) {
#pragma unroll
      for (int ni = 0; ni < NREP; ++ni) {
        const int col = wn * (NREP * 16) + ni * 16 + lr;
        const float bv = bias ? bias[n0 + col] : 0.f;
#pragma unroll
        for (int j = 0; j < 4; ++j) {
          const int row = wm * (MREP * 16) + mi * 16 + (hi << 2) + j;
          cl[row * BN + ((((col >> 3) ^ (row & 7)) << 3) | (col & 7))] =
              (bf16)(acc[mi][ni][j] + bv);
        }
      }
    }
    __syncthreads();
    constexpr int GPR = BN / 8;
    constexpr int PT = BM * GPR / THREADS;
#pragma unroll
    for (int c = 0; c < PT; ++c) {
      const int ch = c * THREADS + tid;
      const int row = ch / GPR, g = ch % GPR;
      bf16x8 vv = *(const bf16x8*)&cl[row * BN + ((g ^ (row & 7)) << 3)];
      *(bf16x8*)&((bf16*)Cout)[(size_t)(m0 + row) * N + n0 + g * 8] = vv;
    }
  }
}

// ---------------------------------------------------------------------------
// fp32 -> bf16 weight conversion (vectorized by 4)
// ---------------------------------------------------------------------------
__global__ void k_f2b4(const float* __restrict__ in, bf16* __restrict__ out, int n4) {
  int i = blockIdx.x * 256 + threadIdx.x;
  if (i >= n4) return;
  float4 v = ((const float4*)in)[i];
  bf16x4 o = {(bf16)v.x, (bf16)v.y, (bf16)v.z, (bf16)v.w};
  ((bf16x4*)out)[i] = o;
}

// hidden fp32 -> hsb bf16, and conv1 interleaved input A1[t][2h+tap]
__global__ void k_build_a1(const float* __restrict__ hid, const float* __restrict__ lf1,
                           bf16* __restrict__ hsb, bf16* __restrict__ A1) {
  int idx = blockIdx.x * 256 + threadIdx.x;  // < T*H
  int t = idx >> 11, h = idx & 2047;
  float x = hid[idx];
  hsb[idx] = (bf16)x;
  float xp;
  if ((t & (Sc - 1)) == 0)
    xp = lf1[(t >> 10) * Hc + h];
  else
    xp = hid[idx - Hc];
  size_t a = ((size_t)t << 12) + 2 * h;
  A1[a] = (bf16)xp;
  A1[a + 1] = (bf16)x;
}

// conv2 interleaved input A2[t][2c+tap] from o1
__global__ void k_build_a2(const bf16* __restrict__ o1, const float* __restrict__ lf2,
                           bf16* __restrict__ A2) {
  int idx = blockIdx.x * 256 + threadIdx.x;  // < T*1024
  int t = idx >> 10, c = idx & 1023;
  bf16 cur = o1[idx];
  bf16 prev;
  if ((t & (Sc - 1)) == 0)
    prev = (bf16)lf2[(t >> 10) * 1024 + c];
  else
    prev = o1[idx - 1024];
  size_t a = ((size_t)t << 11) + 2 * c;
  A2[a] = prev;
  A2[a + 1] = cur;
}

// lf = rmsnorm(o2 + hid) * g   (one block per row, 256 thr x 8 elems)
__global__ __launch_bounds__(256) void k_rmsnorm(const bf16* __restrict__ o2,
                                                 const float* __restrict__ hid,
                                                 const float* __restrict__ g,
                                                 bf16* __restrict__ lf) {
  int t = blockIdx.x, tid = threadIdx.x;
  size_t base = ((size_t)t << 11) + tid * 8;
  bf16x8 ov = *(const bf16x8*)&o2[base];
  const float* hp = &hid[base];
  float vals[8];
  float ss = 0.f;
#pragma unroll
  for (int i = 0; i < 8; ++i) {
    float x = (float)ov[i] + hp[i];
    vals[i] = x;
    ss += x * x;
  }
#pragma unroll
  for (int off = 1; off < 64; off <<= 1) ss += __shfl_xor(ss, off);
  __shared__ float red[4];
  if ((tid & 63) == 0) red[tid >> 6] = ss;
  __syncthreads();
  float tot = red[0] + red[1] + red[2] + red[3];
  float inv = rsqrtf(tot * (1.f / 2048.f) + 1e-6f);
  bf16x8 o;
#pragma unroll
  for (int i = 0; i < 8; ++i) o[i] = (bf16)(vals[i] * inv * g[tid * 8 + i]);
  *(bf16x8*)&lf[base] = o;
}

// RoPE on qk (T,NH,256) -> qr,kr laid out (B,NH,S,HD) bf16
__global__ void k_rope(const bf16* __restrict__ qk, const float* __restrict__ rot,
                       bf16* __restrict__ qr, bf16* __restrict__ kr) {
  int bid = blockIdx.x;  // T*NH
  int n = bid & 15, t = bid >> 4;
  int s = t & (Sc - 1), b = t >> 10;
  int tid = threadIdx.x;
  int isk = tid >> 7, d = tid & 127;
  const bf16* src = qk + ((size_t)t << 12) + n * 256 + isk * 128;
  float val = (float)src[d];
  float outv = val;
  if (d < 64) {
    float f = rot[s * 64 + d];
    float c = cosf(f), sn = sinf(f);
    float other = (float)src[d ^ 32];
    outv = (d < 32) ? (val * c - other * sn) : (val * c + other * sn);
  }
  bf16* dst = isk ? kr : qr;
  dst[((size_t)((b * 16 + n) * 1024 + s) << 7) + d] = (bf16)outv;
}

// v (T,P) -> vT (B,NH,HD,S), 32x32 LDS tile transpose
__global__ void k_vt(const bf16* __restrict__ v, bf16* __restrict__ vT) {
  __shared__ bf16 tile[32][33];
  int bid = blockIdx.x;
  int dt = bid & 3;          // HD/32
  int st = (bid >> 2) & 31;  // S/32
  int bn = bid >> 7;         // b*NH+n
  int b = bn >> 4, n = bn & 15;
  int tx = threadIdx.x & 31, ty = threadIdx.x >> 5;  // 32 x 8
#pragma unroll
  for (int i = 0; i < 4; ++i) {
    int s = st * 32 + ty + i * 8;
    int d = dt * 32 + tx;
    tile[ty + i * 8][tx] = v[(size_t)(b * 1024 + s) * 2048 + n * 128 + d];
  }
  __syncthreads();
#pragma unroll
  for (int i = 0; i < 4; ++i) {
    int d = dt * 32 + ty + i * 8;
    int s = st * 32 + tx;
    vT[((size_t)(bn * 128 + d)) * 1024 + s] = tile[tx][ty + i * 8];
  }
}

// ---------------------------------------------------------------------------
// causal flash attention v2: LDS-staged K/V, double-buffered global_load_lds,
// balanced q-tile pairs (pr, 15-pr), XCD-local (b,h) mapping.
// ---------------------------------------------------------------------------
__global__ __launch_bounds__(256, 2) void k_attn(const bf16* __restrict__ qr,
                                                 const bf16* __restrict__ kr,
                                                 const bf16* __restrict__ vT,
                                                 bf16* __restrict__ att) {
  __shared__ bf16 Ks[2][64 * 128];
  __shared__ bf16 Vs[2][128 * 64];
  __shared__ bf16 plds[4][16 * 64];
  const int bid = blockIdx.x;
  const int xcd = bid & 7, jj = bid >> 3;
  const int bn = xcd * 8 + (jj >> 3);
  const int pr = jj & 7;
  const int tid = threadIdx.x, w = tid >> 6, l = tid & 63;
  const int lr = l & 15, hi = l >> 4;
  const bf16* kb = kr + ((size_t)bn << 17);
  const bf16* vb = vT + ((size_t)bn << 17);
  const int b = bn >> 4, hh = bn & 15;
  const float scaling = 0.08838834764831845f;

  auto stage = [&](int buf, int kt) {
#pragma unroll
    for (int c = 0; c < 4; ++c) {
      int chunk = c * 256 + tid;
      int prow = chunk >> 4, pcg = chunk & 15;
      async16(kb + ((size_t)(kt * 64 + prow) << 7) + ((pcg ^ (prow & 7)) << 3),
              (char*)&Ks[buf][0] + chunk * 16);
    }
#pragma unroll
    for (int c = 0; c < 4; ++c) {
      int chunk = c * 256 + tid;
      int prow = chunk >> 3, pcg = chunk & 7;
      async16(vb + ((size_t)prow << 10) + kt * 64 + ((pcg ^ (prow & 7)) << 3),
              (char*)&Vs[buf][0] + chunk * 16);
    }
  };

#pragma unroll 1
  for (int phase = 0; phase < 2; ++phase) {
    const int qt = phase ? (15 - pr) : pr;
    const int qg0 = qt * 64 + w * 16;
    const bf16* qb = qr + ((size_t)(bn * 1024 + qg0) << 7);
    bf16x8 qf[4];
#pragma unroll
    for (int ks = 0; ks < 4; ++ks) qf[ks] = *(const bf16x8*)&qb[lr * 128 + ks * 32 + hi * 8];
    f32x4 oacc[8] = {};
    float mrow[4] = {-1e30f, -1e30f, -1e30f, -1e30f};
    float lrow[4] = {0.f, 0.f, 0.f, 0.f};
    const int nkb = qt + 1;

    stage(0, 0);
    __syncthreads();

    for (int kbt = 0; kbt < nkb; ++kbt) {
      const int cur = kbt & 1;
      if (kbt + 1 < nkb) stage(cur ^ 1, kbt + 1);

      f32x4 sacc[4] = {};
#pragma unroll
      for (int n = 0; n < 4; ++n) {
        const int krow = n * 16 + lr;
#pragma unroll
        for (int ks = 0; ks < 4; ++ks) {
          bf16x8 kf = *(const bf16x8*)&Ks[cur][(krow << 7) + ((((ks << 2) | hi) ^ (krow & 7)) << 3)];
          sacc[n] = __builtin_amdgcn_mfma_f32_16x16x32_bf16(qf[ks], kf, sacc[n], 0, 0, 0);
        }
      }
      const bool needmask = (kbt * 64 + 63 > qg0);
#pragma unroll
      for (int n = 0; n < 4; ++n) {
        int kg = kbt * 64 + n * 16 + lr;
#pragma unroll
        for (int j = 0; j < 4; ++j) {
          float sv = sacc[n][j] * scaling;
          if (needmask && kg > qg0 + hi * 4 + j) sv = -1e30f;
          sacc[n][j] = sv;
        }
      }
      float sf[4];
#pragma unroll
      for (int j = 0; j < 4; ++j) {
        float pm = fmaxf(fmaxf(sacc[0][j], sacc[1][j]), fmaxf(sacc[2][j], sacc[3][j]));
        pm = fmaxf(pm, __shfl_xor(pm, 1));
        pm = fmaxf(pm, __shfl_xor(pm, 2));
        pm = fmaxf(pm, __shfl_xor(pm, 4));
        pm = fmaxf(pm, __shfl_xor(pm, 8));
        float mn = fmaxf(mrow[j], pm);
        sf[j] = __expf(mrow[j] - mn);
        mrow[j] = mn;
      }
#pragma unroll
      for (int n = 0; n < 4; ++n)
#pragma unroll
        for (int j = 0; j < 4; ++j) sacc[n][j] = __expf(sacc[n][j] - mrow[j]);
#pragma unroll
      for (int j = 0; j < 4; ++j) {
        float ps = sacc[0][j] + sacc[1][j] + sacc[2][j] + sacc[3][j];
        ps += __shfl_xor(ps, 1);
        ps += __shfl_xor(ps, 2);
        ps += __shfl_xor(ps, 4);
        ps += __shfl_xor(ps, 8);
        lrow[j] = lrow[j] * sf[j] + ps;
      }
#pragma unroll
      for (int dt = 0; dt < 8; ++dt)
#pragma unroll
        for (int j = 0; j < 4; ++j) oacc[dt][j] *= sf[j];
#pragma unroll
      for (int n = 0; n < 4; ++n)
#pragma unroll
        for (int j = 0; j < 4; ++j)
          plds[w][(hi * 4 + j) * 64 + n * 16 + lr] = (bf16)sacc[n][j];
      asm volatile("s_waitcnt lgkmcnt(0)" ::: "memory");
#pragma unroll
      for (int ks2 = 0; ks2 < 2; ++ks2) {
        bf16x8 pf = *(const bf16x8*)&plds[w][lr * 64 + ks2 * 32 + hi * 8];
#pragma unroll
        for (int dt = 0; dt < 8; ++dt) {
          const int vrow = dt * 16 + lr;
          bf16x8 vf = *(const bf16x8*)&Vs[cur][(vrow << 6) + ((((ks2 << 2) | hi) ^ (lr & 7)) << 3)];
          oacc[dt] = __builtin_amdgcn_mfma_f32_16x16x32_bf16(pf, vf, oacc[dt], 0, 0, 0);
        }
      }
      __syncthreads();
    }

#pragma unroll
    for (int j = 0; j < 4; ++j) {
      float inv = 1.f / lrow[j];
      int qg = qg0 + hi * 4 + j;
      size_t obase = ((size_t)(b * 1024 + qg) << 11) + hh * 128;
#pragma unroll
      for (int dt = 0; dt < 8; ++dt) att[obase + dt * 16 + lr] = (bf16)(oacc[dt][j] * inv);
    }
  }
}

// ---------------------------------------------------------------------------
// Workspace plan (120 MB total, sequential liveness — one stream, in-order):
//   W    0-16    weight slot (reused: Wv, c1w, c2w, Wqk(16MB), Wo)
//   S0  16-48    A1 (32MB)            -> qkb (32MB)
//   S1  48-64    hsb                  -> lfb      -> vT
//   S2  64-80    v                    -> att
//   S3  80-88    o1
//   S4  88-104   A2                   -> qr
//   S5 104-120   o2                   -> kr
// ---------------------------------------------------------------------------
extern "C" void kernel_launch(void* const* d_in, const int* in_sizes, int n_in,
                              void* d_out, int out_size, void* d_ws, size_t ws_size,
                              hipStream_t stream) {
  const float* hid = (const float*)d_in[1];
  const float* rot = (const float*)d_in[2];
  const float* lf1 = (const float*)d_in[3];
  const float* lf2 = (const float*)d_in[4];
  const float* Wqk = (const float*)d_in[5];
  const float* Wv  = (const float*)d_in[6];
  const float* Wo  = (const float*)d_in[7];
  const float* c1w = (const float*)d_in[8];
  const float* c1b = (const float*)d_in[9];
  const float* c2w = (const float*)d_in[10];
  const float* c2b = (const float*)d_in[11];
  const float* lng = (const float*)d_in[12];
  float* outp = (float*)d_out;
  char* ws = (char*)d_ws;

  const size_t MB = 1ull << 20;
  bf16* Wslot = (bf16*)(ws + 0 * MB);
  bf16* A1    = (bf16*)(ws + 16 * MB);
  bf16* qkb   = A1;
  bf16* hsb   = (bf16*)(ws + 48 * MB);
  bf16* lfb   = hsb;
  bf16* vT    = hsb;
  bf16* v     = (bf16*)(ws + 64 * MB);
  bf16* att   = v;
  bf16* o1    = (bf16*)(ws + 80 * MB);
  bf16* A2    = (bf16*)(ws + 88 * MB);
  bf16* qr    = A2;
  bf16* o2    = (bf16*)(ws + 104 * MB);
  bf16* kr    = o2;

  auto f2b = [&](const float* in, bf16* out, int n) {
    int n4 = n / 4;
    k_f2b4<<<(n4 + 255) / 256, 256, 0, stream>>>(in, out, n4);
  };

  // 1. v = hs @ Wv.T   (M=4096,N=2048,K=2048; 256x128 8-phase -> 256 blocks)
  f2b(Wv, Wslot, 2048 * 2048);
  k_build_a1<<<Tc * Hc / 256, 256, 0, stream>>>(hid, lf1, hsb, A1);
  gemm8<4, 2, 4, 4, true><<<256, 512, 0, stream>>>(hsb, Wslot, v, nullptr, Tc, Pc, Hc);

  // 2. conv1 (as GEMM; M=4096,N=1024,K=4096; 128^2 2-phase, 256 blocks)
  f2b(c1w, Wslot, 1024 * 2048 * 2);
  gemm_pipe<2, 2, 4, 4, true><<<256, 256, 0, stream>>>(A1, Wslot, o1, c1b, Tc, 1024, 4096);

  // 3. conv2 (M=4096,N=2048,K=2048; 256x128 8-phase)
  k_build_a2<<<Tc * 1024 / 256, 256, 0, stream>>>(o1, lf2, A2);
  f2b(c2w, Wslot, 2048 * 1024 * 2);
  gemm8<4, 2, 4, 4, true><<<256, 512, 0, stream>>>(A2, Wslot, o2, c2b, Tc, 2048, 2048);

  // 4. residual + rmsnorm
  k_rmsnorm<<<Tc, 256, 0, stream>>>(o2, hid, lng, lfb);

  // 5. qk projection (M=4096,N=4096,K=2048; 256^2 8-phase -> 256 blocks)
  f2b(Wqk, Wslot, 4096 * 2048);
  gemm8<2, 4, 8, 4, true><<<256, 512, 0, stream>>>(lfb, Wslot, qkb, nullptr, Tc, 4096, Hc);

  // 6. rope, V transpose, attention
  k_rope<<<Tc * NHc, 256, 0, stream>>>(qkb, rot, qr, kr);
  k_vt<<<64 * 32 * 4, 256, 0, stream>>>(v, vT);
  k_attn<<<Bc * NHc * 8, 256, 0, stream>>>(qr, kr, vT, att);

  // 7. output projection (fp32 out; 256x128 8-phase)
  f2b(Wo, Wslot, 2048 * 2048);
  gemm8<4, 2, 4, 4, false><<<256, 512, 0, stream>>>(att, Wslot, outp, nullptr, Tc, 2048, 2048);
}